// Round 14
// baseline (878.580 us; speedup 1.0000x reference)
//
#include <hip/hip_runtime.h>

typedef unsigned short ushort;
typedef unsigned int uint;
typedef __attribute__((ext_vector_type(8))) short short8;
typedef __attribute__((ext_vector_type(4))) float float4v;

#define DEV __device__ __forceinline__

DEV float b2f(ushort u) {
    union { uint i; float f; } v; v.i = ((uint)u) << 16; return v.f;
}
DEV ushort f2b(float f) {
    union { float f; uint i; } v; v.f = f;
    uint x = v.i;
    uint r = x + 0x7fffu + ((x >> 16) & 1u);
    return (ushort)(r >> 16);
}
DEV float leaky(float x, float s) { return x >= 0.f ? x : s * x; }

// ---------------- convert (+local sniff, +zero slice, +flag write) ----------------
struct ConvArgs {
    const void* s[37];
    float* d[37];
    int n[37];
};

__global__ __launch_bounds__(256) void convert_kernel(ConvArgs a, const ushort* __restrict__ x0,
                                                      int* __restrict__ flag) {
    __shared__ int sfp32;
    int tid = threadIdx.x;
    if (tid < 64) {
        int cnt = 0;
        for (int j = 0; j < 8; j++) {
            ushort u = x0[(tid * 8 + j) * 2];
            int e = (u >> 7) & 0xFF;
            if (e >= 100 && e <= 140) cnt++;
        }
#pragma unroll
        for (int m = 1; m < 64; m <<= 1) cnt += __shfl_xor(cnt, m, 64);
        if (tid == 0) sfp32 = (cnt < 256) ? 1 : 0;
    }
    __syncthreads();
    bool fp32 = (sfp32 != 0);
    if (blockIdx.x == 0 && blockIdx.y == 0 && tid == 0) *flag = fp32 ? 1 : 0;

    int ai = blockIdx.y;
    int n = a.n[ai];
    const void* s = a.s[ai];
    float* d = a.d[ai];
    int stride = gridDim.x * blockDim.x;
    if (s == nullptr) {
        for (int i = blockIdx.x * blockDim.x + tid; i < n; i += stride) d[i] = 0.f;
    } else {
        for (int i = blockIdx.x * blockDim.x + tid; i < n; i += stride)
            d[i] = fp32 ? ((const float*)s)[i] : b2f(((const ushort*)s)[i]);
    }
}

// ---------------- CSR build (patch+mesh merged) ----------------
__global__ __launch_bounds__(256) void hist_both(const int* __restrict__ dstP, int* __restrict__ cntP, int EPc,
                                                 const int* __restrict__ dstM, int* __restrict__ cntM, int EMc,
                                                 int PB) {
    bool patch = (int)blockIdx.x < PB;
    const int* dst = patch ? dstP : dstM;
    int* cnt = patch ? cntP : cntM;
    int E = patch ? EPc : EMc;
    int nb = patch ? PB : gridDim.x - PB;
    int b = patch ? blockIdx.x : blockIdx.x - PB;
    int stride = nb * blockDim.x;
    for (int i = b * blockDim.x + threadIdx.x; i < E; i += stride)
        atomicAdd(&cnt[dst[i]], 1);
}

__global__ __launch_bounds__(256) void scan_both(const int* __restrict__ cntP, int* __restrict__ offP,
                                                 int* __restrict__ bsumP, int nP, int SBP,
                                                 const int* __restrict__ cntM, int* __restrict__ offM,
                                                 int* __restrict__ bsumM, int nM) {
    __shared__ int ls[256];
    bool patch = (int)blockIdx.x < SBP;
    const int* cnt = patch ? cntP : cntM;
    int* off = patch ? offP : offM;
    int* bsum = patch ? bsumP : bsumM;
    int n = patch ? nP : nM;
    int b = patch ? blockIdx.x : blockIdx.x - SBP;
    int t = threadIdx.x;
    int base = b * 2048 + t * 8;
    int v[8];
    int s = 0;
#pragma unroll
    for (int i = 0; i < 8; i++) {
        int idx = base + i;
        v[i] = idx < n ? cnt[idx] : 0;
        s += v[i];
    }
    ls[t] = s;
    __syncthreads();
#pragma unroll
    for (int d = 1; d < 256; d <<= 1) {
        int add = (t >= d) ? ls[t - d] : 0;
        __syncthreads();
        ls[t] += add;
        __syncthreads();
    }
    int run = ls[t] - s;
#pragma unroll
    for (int i = 0; i < 8; i++) {
        int idx = base + i;
        if (idx < n) off[idx] = run;
        run += v[i];
    }
    if (t == 255) bsum[b] = ls[255];
}

__global__ __launch_bounds__(256) void fixup_both(const int* __restrict__ bsumP, int* __restrict__ offP,
                                                  int nP, int SBP,
                                                  const int* __restrict__ bsumM, int* __restrict__ offM,
                                                  int nM, int SBM) {
    bool patch = (int)blockIdx.x < SBP;
    const int* bsum = patch ? bsumP : bsumM;
    int* off = patch ? offP : offM;
    int n = patch ? nP : nM;
    int nb = patch ? SBP : SBM;
    int b = patch ? blockIdx.x : blockIdx.x - SBP;
    int t = threadIdx.x;
    int base = 0;
    for (int i = 0; i < b; i++) base += bsum[i];
    int idx0 = b * 2048 + t * 8;
    if (base != 0) {
#pragma unroll
        for (int i = 0; i < 8; i++) {
            int idx = idx0 + i;
            if (idx < n) off[idx] += base;
        }
    }
    if (b == nb - 1 && t == 255) off[n] = base + bsum[b];
}

__global__ __launch_bounds__(256) void scatter_both(const int* __restrict__ srcP, const int* __restrict__ dstP,
                                                    const int* __restrict__ offP, int* __restrict__ curP,
                                                    int* __restrict__ csrP, int EPc,
                                                    const int* __restrict__ srcM, const int* __restrict__ dstM,
                                                    const int* __restrict__ offM, int* __restrict__ curM,
                                                    int* __restrict__ csrM, int EMc, int PB) {
    bool patch = (int)blockIdx.x < PB;
    const int* src = patch ? srcP : srcM;
    const int* dst = patch ? dstP : dstM;
    const int* off = patch ? offP : offM;
    int* cursor = patch ? curP : curM;
    int* csr = patch ? csrP : csrM;
    int E = patch ? EPc : EMc;
    int nb = patch ? PB : gridDim.x - PB;
    int b = patch ? blockIdx.x : blockIdx.x - PB;
    int stride = nb * blockDim.x;
    for (int i = b * blockDim.x + threadIdx.x; i < E; i += stride) {
        int d = dst[i];
        int pos = off[d] + atomicAdd(&cursor[d], 1);
        csr[pos] = src[i];
    }
}

// ---------------- layer-1: el/er only ----------------
__global__ __launch_bounds__(256) void proj1_elr_kernel(const float* __restrict__ x,
                                                        const float* __restrict__ W,
                                                        const float* __restrict__ al,
                                                        const float* __restrict__ ar,
                                                        float* __restrict__ el,
                                                        float* __restrict__ er, int Nn) {
    int t = threadIdx.x;
    int head = t >> 6, lane = t & 63;
    float wv[5];
#pragma unroll
    for (int k = 0; k < 5; k++) wv[k] = W[k * 256 + t];
    float alv = al[t];
    float arv = ar[t];
    int n0 = blockIdx.x * 4;
    int n1 = min(n0 + 4, Nn);
    for (int n = n0; n < n1; n++) {
        float acc = 0.f;
#pragma unroll
        for (int k = 0; k < 5; k++) acc += x[n * 5 + k] * wv[k];
        float pl = acc * alv, pr = acc * arv;
#pragma unroll
        for (int m = 1; m < 64; m <<= 1) {
            pl += __shfl_xor(pl, m, 64);
            pr += __shfl_xor(pr, m, 64);
        }
        if (lane == 0) { el[n * 4 + head] = pl; er[n * 4 + head] = pr; }
    }
}

// ---------------- patch layer-1 aggregation: outer-product, 3 dst per wave ----------------
__global__ __launch_bounds__(256, 4) void aggr1_fly_kernel(const float* __restrict__ x,
                                                           const float* __restrict__ W,
                                                           const float* __restrict__ el,
                                                           const float* __restrict__ er,
                                                           const int* __restrict__ off,
                                                           const int* __restrict__ csr,
                                                           float* __restrict__ out, int Nn) {
    int wid = threadIdx.x >> 6;
    int lane = threadIdx.x & 63;
    int grp = lane / 20;          // 0..3 (grp 3 idle for edge work)
    int gl = lane - grp * 20;
    int dbase = blockIdx.x * 12 + wid * 3;
    int d = dbase + grp;
    bool accl = (grp < 3) && (d < Nn);
    int dd = accl ? d : 0;
    int h_ = gl / 5, k_ = gl - h_ * 5;  // h_ 0..3, k_ 0..4
    int c0 = lane * 4;
    int myhead = lane >> 4;
    float w0[5], w1[5], w2[5], w3[5];
#pragma unroll
    for (int k = 0; k < 5; k++) {
        float4 wv = *(const float4*)(W + k * 256 + c0);
        w0[k] = wv.x; w1[k] = wv.y; w2[k] = wv.z; w3[k] = wv.w;
    }
    float erd = accl ? er[dd * 4 + h_] : 0.f;
    float acc = 0.f, sh = 0.f;
    int e = accl ? off[dd] : 0;
    int e1 = accl ? off[dd + 1] : 0;
#define A1_ACC(XV, EV)                                  \
    {                                                   \
        float e0_ = (EV) + erd;                         \
        e0_ = e0_ >= 0.f ? e0_ : 0.2f * e0_;            \
        float w_ = __expf(fminf(e0_, 80.f));            \
        acc += w_ * (XV);                               \
        sh += w_;                                       \
    }
    for (; e + 4 <= e1; e += 4) {
        int s0 = csr[e], s1 = csr[e + 1], s2 = csr[e + 2], s3 = csr[e + 3];
        float x0 = x[s0 * 5 + k_];
        float x1 = x[s1 * 5 + k_];
        float x2 = x[s2 * 5 + k_];
        float x3 = x[s3 * 5 + k_];
        float v0 = el[s0 * 4 + h_];
        float v1 = el[s1 * 4 + h_];
        float v2 = el[s2 * 4 + h_];
        float v3 = el[s3 * 4 + h_];
        A1_ACC(x0, v0) A1_ACC(x1, v1) A1_ACC(x2, v2) A1_ACC(x3, v3)
    }
    for (; e < e1; e++) {
        int s0 = csr[e];
        float x0 = x[s0 * 5 + k_];
        float v0 = el[s0 * 4 + h_];
        A1_ACC(x0, v0)
    }
#undef A1_ACC
    // epilogue: for each of the 3 dsts, broadcast acc[h][:] and project through W
#pragma unroll
    for (int g3 = 0; g3 < 3; g3++) {
        int dsto = dbase + g3;
        if (dsto >= Nn) break;  // wave-uniform
        float a_k[5];
#pragma unroll
        for (int k = 0; k < 5; k++) a_k[k] = __shfl(acc, g3 * 20 + myhead * 5 + k, 64);
        float s = __shfl(sh, g3 * 20 + myhead * 5, 64);
        float inv = 1.f / fmaxf(s, 1e-9f);
        float o0 = 0.f, o1 = 0.f, o2 = 0.f, o3 = 0.f;
#pragma unroll
        for (int k = 0; k < 5; k++) {
            o0 += a_k[k] * w0[k]; o1 += a_k[k] * w1[k];
            o2 += a_k[k] * w2[k]; o3 += a_k[k] * w3[k];
        }
        float4 o;
        o.x = leaky(o0 * inv, 0.01f);
        o.y = leaky(o1 * inv, 0.01f);
        o.z = leaky(o2 * inv, 0.01f);
        o.w = leaky(o3 * inv, 0.01f);
        *(float4*)(out + (size_t)dsto * 256 + c0) = o;
    }
}

// ---------------- gather aggregation: 2 dst/wave, 8 cols/lane (bf16 in, fp32 out) ----------------
template <int H, int LOGD, int HD>
__global__ __launch_bounds__(256, 4) void aggr4_kernel(const ushort* __restrict__ h,
                                                       const float* __restrict__ el,
                                                       const float* __restrict__ er,
                                                       const int* __restrict__ off,
                                                       const int* __restrict__ csr,
                                                       float* __restrict__ out, int Nn,
                                                       float oslope) {
    int wid = threadIdx.x >> 6;
    int lane = threadIdx.x & 63;
    int half = lane >> 5, hl = lane & 31;
    constexpr int NL = HD / 8;
    int d = blockIdx.x * 8 + wid * 2 + half;
    bool valid = (hl < NL) && (d < Nn);
    int dd = valid ? d : 0;
    int myhead = (hl * 8) >> LOGD;
    float erd = valid ? er[dd * H + myhead] : 0.f;
    float a0 = 0.f, a1 = 0.f, a2 = 0.f, a3 = 0.f;
    float a4 = 0.f, a5 = 0.f, a6 = 0.f, a7 = 0.f, s = 0.f;
    int e = valid ? off[dd] : 0;
    int e1 = valid ? off[dd + 1] : 0;
#define A8_ACC(EV, HR)                                      \
    {                                                       \
        float ev_ = (EV) + erd;                             \
        ev_ = ev_ >= 0.f ? ev_ : 0.2f * ev_;                \
        float w_ = __expf(fminf(ev_, 80.f));                \
        a0 += w_ * b2f((ushort)(HR).x);                     \
        a1 += w_ * b2f((ushort)((HR).x >> 16));             \
        a2 += w_ * b2f((ushort)(HR).y);                     \
        a3 += w_ * b2f((ushort)((HR).y >> 16));             \
        a4 += w_ * b2f((ushort)(HR).z);                     \
        a5 += w_ * b2f((ushort)((HR).z >> 16));             \
        a6 += w_ * b2f((ushort)(HR).w);                     \
        a7 += w_ * b2f((ushort)((HR).w >> 16));             \
        s += w_;                                            \
    }
#define A8_ACCM(OK, EV, HR)                                 \
    {                                                       \
        float ev_ = (EV) + erd;                             \
        ev_ = ev_ >= 0.f ? ev_ : 0.2f * ev_;                \
        float w_ = (OK) ? __expf(fminf(ev_, 80.f)) : 0.f;   \
        a0 += w_ * b2f((ushort)(HR).x);                     \
        a1 += w_ * b2f((ushort)((HR).x >> 16));             \
        a2 += w_ * b2f((ushort)(HR).y);                     \
        a3 += w_ * b2f((ushort)((HR).y >> 16));             \
        a4 += w_ * b2f((ushort)(HR).z);                     \
        a5 += w_ * b2f((ushort)((HR).z >> 16));             \
        a6 += w_ * b2f((ushort)(HR).w);                     \
        a7 += w_ * b2f((ushort)((HR).w >> 16));             \
        s += w_;                                            \
    }
    for (; e + 4 <= e1; e += 4) {
        int s0 = csr[e], s1 = csr[e + 1], s2 = csr[e + 2], s3 = csr[e + 3];
        float e0 = el[s0 * H + myhead];
        float e1v = el[s1 * H + myhead];
        float e2v = el[s2 * H + myhead];
        float e3v = el[s3 * H + myhead];
        uint4 h0 = *(const uint4*)(h + (size_t)s0 * HD + hl * 8);
        uint4 h1 = *(const uint4*)(h + (size_t)s1 * HD + hl * 8);
        uint4 h2 = *(const uint4*)(h + (size_t)s2 * HD + hl * 8);
        uint4 h3 = *(const uint4*)(h + (size_t)s3 * HD + hl * 8);
        A8_ACC(e0, h0) A8_ACC(e1v, h1) A8_ACC(e2v, h2) A8_ACC(e3v, h3)
    }
    if (e < e1) {
        bool k1 = e + 1 < e1, k2 = e + 2 < e1, k3 = e + 3 < e1;
        int s0 = csr[e];
        int s1 = csr[k1 ? e + 1 : e];
        int s2 = csr[k2 ? e + 2 : e];
        int s3 = csr[k3 ? e + 3 : e];
        float e0 = el[s0 * H + myhead];
        float e1v = el[s1 * H + myhead];
        float e2v = el[s2 * H + myhead];
        float e3v = el[s3 * H + myhead];
        uint4 h0 = *(const uint4*)(h + (size_t)s0 * HD + hl * 8);
        uint4 h1 = *(const uint4*)(h + (size_t)s1 * HD + hl * 8);
        uint4 h2 = *(const uint4*)(h + (size_t)s2 * HD + hl * 8);
        uint4 h3 = *(const uint4*)(h + (size_t)s3 * HD + hl * 8);
        A8_ACCM(true, e0, h0) A8_ACCM(k1, e1v, h1) A8_ACCM(k2, e2v, h2) A8_ACCM(k3, e3v, h3)
    }
#undef A8_ACC
#undef A8_ACCM
    if (valid) {
        float inv = 1.f / fmaxf(s, 1e-9f);
        float4 oa, ob;
        oa.x = leaky(a0 * inv, oslope);
        oa.y = leaky(a1 * inv, oslope);
        oa.z = leaky(a2 * inv, oslope);
        oa.w = leaky(a3 * inv, oslope);
        ob.x = leaky(a4 * inv, oslope);
        ob.y = leaky(a5 * inv, oslope);
        ob.z = leaky(a6 * inv, oslope);
        ob.w = leaky(a7 * inv, oslope);
        float* po = out + (size_t)dd * HD + hl * 8;
        *(float4*)(po) = oa;
        *(float4*)(po + 4) = ob;
    }
}

// final GAT layer: H=2, D=32, HD=64 — 4 dst/wave (16 lanes, 4 cols/lane), scalarized U=8
__global__ __launch_bounds__(256, 4) void aggr_mean_kernel(const ushort* __restrict__ h,
                                                           const float* __restrict__ el,
                                                           const float* __restrict__ er,
                                                           const int* __restrict__ off,
                                                           const int* __restrict__ csr,
                                                           const int* __restrict__ gid,
                                                           float* __restrict__ out_sum,
                                                           float* __restrict__ out_cnt,
                                                           int Nn) {
    int wid = threadIdx.x >> 6;
    int lane = threadIdx.x & 63;
    int qtr = lane >> 4;       // 0..3: dst within wave
    int ql = lane & 15;        // cols 4ql .. 4ql+3
    int d = blockIdx.x * 16 + wid * 4 + qtr;
    bool valid = d < Nn;
    int dd = valid ? d : 0;
    int head = ql >> 3;        // cols<32 -> head0, cols>=32 -> head1
    float erd = er[dd * 2 + head];
    float a0 = 0.f, a1 = 0.f, a2 = 0.f, a3 = 0.f, s = 0.f;
    int e = valid ? off[dd] : 0;
    int e1 = valid ? off[dd + 1] : 0;
#define AM_ACC(Q, V)                                        \
    {                                                       \
        float ev_ = (head ? (Q).y : (Q).x) + erd;           \
        ev_ = ev_ >= 0.f ? ev_ : 0.2f * ev_;                \
        float w_ = __expf(fminf(ev_, 80.f));                \
        a0 += w_ * b2f((ushort)(V).x);                      \
        a1 += w_ * b2f((ushort)((V).x >> 16));              \
        a2 += w_ * b2f((ushort)(V).y);                      \
        a3 += w_ * b2f((ushort)((V).y >> 16));              \
        s += w_;                                            \
    }
#define AM_ACCM(OK, Q, V)                                   \
    {                                                       \
        float ev_ = (head ? (Q).y : (Q).x) + erd;           \
        ev_ = ev_ >= 0.f ? ev_ : 0.2f * ev_;                \
        float w_ = (OK) ? __expf(fminf(ev_, 80.f)) : 0.f;   \
        a0 += w_ * b2f((ushort)(V).x);                      \
        a1 += w_ * b2f((ushort)((V).x >> 16));              \
        a2 += w_ * b2f((ushort)(V).y);                      \
        a3 += w_ * b2f((ushort)((V).y >> 16));              \
        s += w_;                                            \
    }
    for (; e + 8 <= e1; e += 8) {
        int s0 = csr[e], s1 = csr[e + 1], s2 = csr[e + 2], s3 = csr[e + 3];
        int s4 = csr[e + 4], s5 = csr[e + 5], s6 = csr[e + 6], s7 = csr[e + 7];
        float2 q0 = *(const float2*)(el + s0 * 2);
        float2 q1 = *(const float2*)(el + s1 * 2);
        float2 q2 = *(const float2*)(el + s2 * 2);
        float2 q3 = *(const float2*)(el + s3 * 2);
        float2 q4 = *(const float2*)(el + s4 * 2);
        float2 q5 = *(const float2*)(el + s5 * 2);
        float2 q6 = *(const float2*)(el + s6 * 2);
        float2 q7 = *(const float2*)(el + s7 * 2);
        uint2 v0 = *(const uint2*)(h + (size_t)s0 * 64 + ql * 4);
        uint2 v1 = *(const uint2*)(h + (size_t)s1 * 64 + ql * 4);
        uint2 v2 = *(const uint2*)(h + (size_t)s2 * 64 + ql * 4);
        uint2 v3 = *(const uint2*)(h + (size_t)s3 * 64 + ql * 4);
        uint2 v4 = *(const uint2*)(h + (size_t)s4 * 64 + ql * 4);
        uint2 v5 = *(const uint2*)(h + (size_t)s5 * 64 + ql * 4);
        uint2 v6 = *(const uint2*)(h + (size_t)s6 * 64 + ql * 4);
        uint2 v7 = *(const uint2*)(h + (size_t)s7 * 64 + ql * 4);
        AM_ACC(q0, v0) AM_ACC(q1, v1) AM_ACC(q2, v2) AM_ACC(q3, v3)
        AM_ACC(q4, v4) AM_ACC(q5, v5) AM_ACC(q6, v6) AM_ACC(q7, v7)
    }
    if (e < e1) {
        bool k1 = e + 1 < e1, k2 = e + 2 < e1, k3 = e + 3 < e1;
        bool k4 = e + 4 < e1, k5 = e + 5 < e1, k6 = e + 6 < e1, k7 = e + 7 < e1;
        int s0 = csr[e];
        int s1 = csr[k1 ? e + 1 : e];
        int s2 = csr[k2 ? e + 2 : e];
        int s3 = csr[k3 ? e + 3 : e];
        int s4 = csr[k4 ? e + 4 : e];
        int s5 = csr[k5 ? e + 5 : e];
        int s6 = csr[k6 ? e + 6 : e];
        int s7 = csr[k7 ? e + 7 : e];
        float2 q0 = *(const float2*)(el + s0 * 2);
        float2 q1 = *(const float2*)(el + s1 * 2);
        float2 q2 = *(const float2*)(el + s2 * 2);
        float2 q3 = *(const float2*)(el + s3 * 2);
        float2 q4 = *(const float2*)(el + s4 * 2);
        float2 q5 = *(const float2*)(el + s5 * 2);
        float2 q6 = *(const float2*)(el + s6 * 2);
        float2 q7 = *(const float2*)(el + s7 * 2);
        uint2 v0 = *(const uint2*)(h + (size_t)s0 * 64 + ql * 4);
        uint2 v1 = *(const uint2*)(h + (size_t)s1 * 64 + ql * 4);
        uint2 v2 = *(const uint2*)(h + (size_t)s2 * 64 + ql * 4);
        uint2 v3 = *(const uint2*)(h + (size_t)s3 * 64 + ql * 4);
        uint2 v4 = *(const uint2*)(h + (size_t)s4 * 64 + ql * 4);
        uint2 v5 = *(const uint2*)(h + (size_t)s5 * 64 + ql * 4);
        uint2 v6 = *(const uint2*)(h + (size_t)s6 * 64 + ql * 4);
        uint2 v7 = *(const uint2*)(h + (size_t)s7 * 64 + ql * 4);
        AM_ACCM(true, q0, v0) AM_ACCM(k1, q1, v1) AM_ACCM(k2, q2, v2) AM_ACCM(k3, q3, v3)
        AM_ACCM(k4, q4, v4) AM_ACCM(k5, q5, v5) AM_ACCM(k6, q6, v6) AM_ACCM(k7, q7, v7)
    }
#undef AM_ACC
#undef AM_ACCM
    float inv = 1.f / fmaxf(s, 1e-9f);
    float y0 = a0 * inv, y1 = a1 * inv, y2 = a2 * inv, y3 = a3 * inv;
    // head-mean: col c (ql<8) pairs with col c+32 (ql+8), within same quarter
    float p0 = __shfl(y0, lane + 8, 64);
    float p1 = __shfl(y1, lane + 8, 64);
    float p2 = __shfl(y2, lane + 8, 64);
    float p3 = __shfl(y3, lane + 8, 64);
    if (valid && ql < 8) {
        int base = gid ? gid[d] * 32 : 0;
        atomicAdd(&out_sum[base + 4 * ql + 0], 0.5f * (y0 + p0));
        atomicAdd(&out_sum[base + 4 * ql + 1], 0.5f * (y1 + p1));
        atomicAdd(&out_sum[base + 4 * ql + 2], 0.5f * (y2 + p2));
        atomicAdd(&out_sum[base + 4 * ql + 3], 0.5f * (y3 + p3));
        if (ql == 0 && out_cnt) atomicAdd(&out_cnt[gid[d]], 1.0f);
    }
}

// ---------------- GraphNorm column stats (fp32 input, 8-row unroll, scalarized) ----------------
__global__ void colstats_kernel(const float* __restrict__ x,
                                float* __restrict__ sum,
                                float* __restrict__ sumsq, int Nn) {
    int C = blockDim.x, c = threadIdx.x;
    int nb = gridDim.x;
    int chunk = (Nn + nb - 1) / nb;
    int r0 = blockIdx.x * chunk;
    int r1 = min(r0 + chunk, Nn);
    float ls = 0.f, lq = 0.f;
    int r = r0;
    for (; r + 8 <= r1; r += 8) {
        const float* p = x + (size_t)r * C + c;
        float v0 = p[0];
        float v1 = p[C];
        float v2 = p[2 * C];
        float v3 = p[3 * C];
        float v4 = p[4 * C];
        float v5 = p[5 * C];
        float v6 = p[6 * C];
        float v7 = p[7 * C];
        ls += ((v0 + v1) + (v2 + v3)) + ((v4 + v5) + (v6 + v7));
        lq += ((v0 * v0 + v1 * v1) + (v2 * v2 + v3 * v3)) +
              ((v4 * v4 + v5 * v5) + (v6 * v6 + v7 * v7));
    }
    for (; r < r1; r++) {
        float v = x[(size_t)r * C + c];
        ls += v; lq += v * v;
    }
    atomicAdd(&sum[c], ls);
    atomicAdd(&sumsq[c], lq);
}

// GraphNorm apply for readout: writes d_out (per flag) + fp32 mesh input
__global__ void gnorm_apply_ro_kernel(const float* __restrict__ x,
                                      const float* __restrict__ sum,
                                      const float* __restrict__ sumsq,
                                      const float* __restrict__ g,
                                      const float* __restrict__ b,
                                      const float* __restrict__ a,
                                      void* __restrict__ doutv,
                                      const int* __restrict__ flag,
                                      float* __restrict__ rof, int Nn) {
    int c = threadIdx.x;  // C = 32
    float invn = 1.f / (float)Nn;
    float mu = sum[c] * invn, ex2 = sumsq[c] * invn;
    float av = a[c];
    float var = ex2 - 2.f * av * mu * mu + av * av * mu * mu;
    float sc = g[c] * rsqrtf(var + 1e-5f);
    float sh = b[c] - sc * av * mu;
    bool fp32 = (*flag != 0);
    for (int r = blockIdx.x; r < Nn; r += gridDim.x) {
        int i = r * 32 + c;
        float v = x[i] * sc + sh;
        rof[i] = v;
        if (fp32) ((float*)doutv)[15 + i] = v;
        else      ((ushort*)doutv)[15 + i] = f2b(v);
    }
}

// ---------------- readout: segment-mean @ pcls + leaky (fp32 out) ----------------
__global__ __launch_bounds__(256) void readout_kernel(const float* __restrict__ ro_sum,
                                                      const float* __restrict__ ro_cnt,
                                                      const float* __restrict__ pcls,
                                                      float* __restrict__ ro_lin, int NGc) {
    int idx = blockIdx.x * blockDim.x + threadIdx.x;
    int g = idx >> 5, c = idx & 31;
    if (g >= NGc) return;
    float inv = 1.f / fmaxf(ro_cnt[g], 1.f);
    float acc = 0.f;
#pragma unroll
    for (int k = 0; k < 32; k++) acc += ro_sum[g * 32 + k] * inv * pcls[k * 32 + c];
    ro_lin[g * 32 + c] = leaky(acc, 0.01f);
}

// ---------------- MFMA GEMM: C(bf16) = gnorm(A:fp32) @ B, fused gnfin + elr ----------------
template <int K, int N, int H, int LOGD, bool GN>
__global__ __launch_bounds__(256) void gemm_kernel(const float* __restrict__ A,
                                                   const float* __restrict__ B,
                                                   const float* __restrict__ csum,
                                                   const float* __restrict__ g,
                                                   const float* __restrict__ gb,
                                                   const float* __restrict__ ga,
                                                   const float* __restrict__ al,
                                                   const float* __restrict__ ar,
                                                   ushort* __restrict__ C,
                                                   float* __restrict__ el,
                                                   float* __restrict__ er, int M) {
    constexpr int NT = N / 16;
    constexpr int AROW = 40;
    __shared__ __align__(16) ushort Alds[64 * AROW];
    __shared__ __align__(16) ushort Blds[32 * N];  // swizzled [k/8][n][k%8]
    __shared__ float ScL[256], ShL[256];
    int tid = threadIdx.x;
    int w = tid >> 6, lane = tid & 63, q = lane >> 4, l16 = lane & 15;
    int m0 = blockIdx.x * 64;
    if (GN && tid < K) {
        float invn = 1.f / (float)M;
        float mu = csum[tid] * invn, ex2 = csum[512 + tid] * invn;
        float av = ga[tid];
        float var = ex2 - 2.f * av * mu * mu + av * av * mu * mu;
        float sc = g[tid] * rsqrtf(var + 1e-5f);
        ScL[tid] = sc;
        ShL[tid] = gb[tid] - sc * av * mu;
    }
    float4v acc[NT];
#pragma unroll
    for (int nt = 0; nt < NT; nt++) acc[nt] = (float4v){0.f, 0.f, 0.f, 0.f};

    for (int kc = 0; kc < K; kc += 32) {
        __syncthreads();
        {
#pragma unroll
            for (int it = 0; it < 2; it++) {
                int idx = it * 256 + tid;
                int r = idx >> 3;
                int c4 = (idx & 7) * 4;
                int gr = m0 + r;
                float4 av = {0.f, 0.f, 0.f, 0.f};
                if (gr < M) av = *(const float4*)(A + (size_t)gr * K + kc + c4);
                if (GN) {
                    av.x = av.x * ScL[kc + c4] + ShL[kc + c4];
                    av.y = av.y * ScL[kc + c4 + 1] + ShL[kc + c4 + 1];
                    av.z = av.z * ScL[kc + c4 + 2] + ShL[kc + c4 + 2];
                    av.w = av.w * ScL[kc + c4 + 3] + ShL[kc + c4 + 3];
                }
                uint2 pk;
                pk.x = (uint)f2b(av.x) | ((uint)f2b(av.y) << 16);
                pk.y = (uint)f2b(av.z) | ((uint)f2b(av.w) << 16);
                *(uint2*)(&Alds[r * AROW + c4]) = pk;
            }
        }
        {
            constexpr int PAIRS = 16 * N;
#pragma unroll
            for (int p0 = 0; p0 < PAIRS; p0 += 256) {
                int p = p0 + tid;
                int k_ = p / (N / 2);
                int n0 = (p % (N / 2)) * 2;
                float2 bv = *(const float2*)(B + (size_t)(kc + k_) * N + n0);
                int base = (((k_ >> 3) * N + n0) << 3) + (k_ & 7);
                Blds[base] = f2b(bv.x);
                Blds[base + 8] = f2b(bv.y);
            }
        }
        __syncthreads();
        short8 a = *(const short8*)(&Alds[(w * 16 + l16) * AROW + q * 8]);
#pragma unroll
        for (int nt = 0; nt < NT; nt++) {
            short8 b = *(const short8*)(&Blds[(q * N + nt * 16 + l16) * 8]);
            acc[nt] = __builtin_amdgcn_mfma_f32_16x16x32_bf16(a, b, acc[nt], 0, 0, 0);
        }
    }
    // store C (bf16) + fused el/er
    float pel[4][H], per[4][H];
#pragma unroll
    for (int i = 0; i < 4; i++)
#pragma unroll
        for (int hh = 0; hh < H; hh++) { pel[i][hh] = 0.f; per[i][hh] = 0.f; }
#pragma unroll
    for (int nt = 0; nt < NT; nt++) {
        int col = nt * 16 + l16;
        float alc = al[col], arc = ar[col];
        constexpr int HSH = LOGD - 4;
        int hh = nt >> HSH;
#pragma unroll
        for (int i = 0; i < 4; i++) {
            int row = m0 + w * 16 + q * 4 + i;
            float v = acc[nt][i];
            if (row < M) C[(size_t)row * N + col] = f2b(v);
            pel[i][hh] += v * alc;
            per[i][hh] += v * arc;
        }
    }
#pragma unroll
    for (int i = 0; i < 4; i++) {
#pragma unroll
        for (int hh = 0; hh < H; hh++) {
            float vl = pel[i][hh], vr = per[i][hh];
#pragma unroll
            for (int m = 1; m < 16; m <<= 1) {
                vl += __shfl_xor(vl, m, 64);
                vr += __shfl_xor(vr, m, 64);
            }
            if (l16 == 0) {
                int row = m0 + w * 16 + q * 4 + i;
                if (row < M) { el[row * H + hh] = vl; er[row * H + hh] = vr; }
            }
        }
    }
}

// ---------------- final: node-mean @ mcls ----------------
__global__ __launch_bounds__(64) void final_kernel(const float* __restrict__ msum,
                                                   const float* __restrict__ mcls,
                                                   void* __restrict__ doutv,
                                                   const int* __restrict__ flag, int Nm) {
    int t = threadIdx.x;
    if (t < 15) {
        float inv = 1.f / (float)Nm;
        float acc = 0.f;
#pragma unroll
        for (int c = 0; c < 32; c++) acc += msum[c] * inv * mcls[c * 15 + t];
        if (*flag) ((float*)doutv)[t] = acc;
        else       ((ushort*)doutv)[t] = f2b(acc);
    }
}

extern "C" void kernel_launch(void* const* d_in, const int* in_sizes, int n_in,
                              void* d_out, int out_size, void* d_ws, size_t ws_size,
                              hipStream_t stream) {
    const int NP = 100000, NG = 2000, EP = 800000, NM = 2000, EM = 32000;

    const int* patch_src = (const int*)d_in[1];
    const int* patch_dst = (const int*)d_in[2];
    const int* patch_gid = (const int*)d_in[3];
    const int* mesh_src = (const int*)d_in[4];
    const int* mesh_dst = (const int*)d_in[5];

    char* p = (char*)d_ws;
    auto alloc = [&](size_t bytes) -> char* {
        char* r = p;
        p += (bytes + 255) & ~(size_t)255;
        return r;
    };
    char* zbase = p;
    int* cnt_p = (int*)alloc((size_t)NP * 4);
    int* cursor_p = (int*)alloc((size_t)NP * 4);
    int* cnt_m = (int*)alloc((size_t)NM * 4);
    int* cursor_m = (int*)alloc((size_t)NM * 4);
    float* ro_sum = (float*)alloc((size_t)NG * 32 * 4);
    float* ro_cnt = (float*)alloc((size_t)NG * 4);
    float* msum = (float*)alloc(32 * 4);
    float* colbuf = (float*)alloc(6 * 1024 * 4);
    size_t zbytes = (size_t)(p - zbase);
    int* flag = (int*)alloc(256);
    int* off_p = (int*)alloc((size_t)(NP + 1) * 4);
    int* off_m = (int*)alloc((size_t)(NM + 1) * 4);
    int* bsum_p = (int*)alloc(64 * 4);
    int* bsum_m = (int*)alloc(16 * 4);
    int* csr_p = (int*)alloc((size_t)EP * 4);
    int* csr_m = (int*)alloc((size_t)EM * 4);
    float* el = (float*)alloc((size_t)NP * 4 * 4);
    float* er = (float*)alloc((size_t)NP * 4 * 4);
    ushort* hbuf = (ushort*)alloc((size_t)NP * 256 * 2);   // bf16 gather buffer
    float* gbuf = (float*)alloc((size_t)NP * 256 * 4);     // fp32 aggr output
    ushort* hm = (ushort*)alloc((size_t)NM * 256 * 2);
    float* gm = (float*)alloc((size_t)NM * 256 * 4);
    float* elm = (float*)alloc((size_t)NM * 4 * 4);
    float* erm = (float*)alloc((size_t)NM * 4 * 4);
    float* ro_lin = (float*)alloc((size_t)NG * 32 * 4);
    float* ro_f = (float*)alloc((size_t)NG * 32 * 4);

    ConvArgs ca;
    float* convp[36];
    int conv_idx[36];
    conv_idx[0] = 0;
    for (int i = 1; i < 36; i++) conv_idx[i] = 5 + i;
    for (int j = 0; j < 36; j++) {
        int ii = conv_idx[j];
        int n = in_sizes[ii];
        float* dd = (float*)alloc((size_t)n * 4);
        ca.s[j] = d_in[ii];
        ca.d[j] = dd;
        ca.n[j] = n;
        convp[j] = dd;
    }
    ca.s[36] = nullptr;
    ca.d[36] = (float*)zbase;
    ca.n[36] = (int)(zbytes / 4);

    const float* xf = convp[0];
    const float *pW1f = convp[1], *pal1f = convp[2], *par1f = convp[3];
    const float *pg1_gf = convp[4], *pg1_bf = convp[5], *pg1_af = convp[6];
    const float *pW2f = convp[7], *pal2f = convp[8], *par2f = convp[9];
    const float *pg2_gf = convp[10], *pg2_bf = convp[11], *pg2_af = convp[12];
    const float *pW3f = convp[13], *pal3f = convp[14], *par3f = convp[15];
    const float* pclsf = convp[16];
    const float *rn_gf = convp[17], *rn_bf2 = convp[18], *rn_af = convp[19];
    const float *mW1f = convp[20], *mal1f = convp[21], *mar1f = convp[22];
    const float *mg1_gf = convp[23], *mg1_bf = convp[24], *mg1_af = convp[25];
    const float *mW2f = convp[26], *mal2f = convp[27], *mar2f = convp[28];
    const float *mg2_gf = convp[29], *mg2_bf = convp[30], *mg2_af = convp[31];
    const float *mW3f = convp[32], *mal3f = convp[33], *mar3f = convp[34];
    const float* mclsf = convp[35];

    convert_kernel<<<dim3(16, 37), 256, 0, stream>>>(ca, (const ushort*)d_in[0], flag);

    const int SBP = (NP + 2047) / 2048, SBM = (NM + 2047) / 2048;
    hist_both<<<512 + 64, 256, 0, stream>>>(patch_dst, cnt_p, EP, mesh_dst, cnt_m, EM, 512);
    scan_both<<<SBP + SBM, 256, 0, stream>>>(cnt_p, off_p, bsum_p, NP, SBP, cnt_m, off_m, bsum_m, NM);
    fixup_both<<<SBP + SBM, 256, 0, stream>>>(bsum_p, off_p, NP, SBP, bsum_m, off_m, NM, SBM);
    scatter_both<<<512 + 64, 256, 0, stream>>>(patch_src, patch_dst, off_p, cursor_p, csr_p, EP,
                                               mesh_src, mesh_dst, off_m, cursor_m, csr_m, EM, 512);

    int gP = (NP + 3) / 4;
    int gP12 = (NP + 11) / 12;
    int gA2 = (NP + 7) / 8, gA2m = (NM + 7) / 8;
    int gP4 = (NP + 15) / 16, gM4 = (NM + 15) / 16;
    int gT = (NP + 63) / 64, gTm = (NM + 63) / 64;
    float* cb0 = colbuf + 0 * 1024;
    float* cb1 = colbuf + 1 * 1024;
    float* cb2 = colbuf + 2 * 1024;
    float* cb3 = colbuf + 3 * 1024;
    float* cb4 = colbuf + 4 * 1024;

    // ---- patch GAT layer 1 ----
    proj1_elr_kernel<<<gP, 256, 0, stream>>>(xf, pW1f, pal1f, par1f, el, er, NP);
    aggr1_fly_kernel<<<gP12, 256, 0, stream>>>(xf, pW1f, el, er, off_p, csr_p, gbuf, NP);
    colstats_kernel<<<512, 256, 0, stream>>>(gbuf, cb0, cb0 + 512, NP);

    // ---- patch GAT layer 2 ----
    gemm_kernel<256, 192, 3, 6, true><<<gT, 256, 0, stream>>>(
        gbuf, pW2f, cb0, pg1_gf, pg1_bf, pg1_af, pal2f, par2f, hbuf, el, er, NP);
    aggr4_kernel<3, 6, 192><<<gA2, 256, 0, stream>>>(hbuf, el, er, off_p, csr_p, gbuf, NP, 0.01f);
    colstats_kernel<<<512, 192, 0, stream>>>(gbuf, cb1, cb1 + 512, NP);

    // ---- patch GAT layer 3 + readout ----
    gemm_kernel<192, 64, 2, 5, true><<<gT, 256, 0, stream>>>(
        gbuf, pW3f, cb1, pg2_gf, pg2_bf, pg2_af, pal3f, par3f, hbuf, el, er, NP);
    aggr_mean_kernel<<<gP4, 256, 0, stream>>>(hbuf, el, er, off_p, csr_p, patch_gid,
                                              ro_sum, ro_cnt, NP);

    readout_kernel<<<(NG * 32 + 255) / 256, 256, 0, stream>>>(ro_sum, ro_cnt, pclsf, ro_lin, NG);
    colstats_kernel<<<64, 32, 0, stream>>>(ro_lin, cb2, cb2 + 512, NG);
    gnorm_apply_ro_kernel<<<64, 32, 0, stream>>>(ro_lin, cb2, cb2 + 512, rn_gf, rn_bf2, rn_af,
                                                 d_out, flag, ro_f, NG);

    // ---- mesh GAT layer 1 ----
    gemm_kernel<32, 256, 4, 6, false><<<gTm, 256, 0, stream>>>(
        ro_f, mW1f, nullptr, nullptr, nullptr, nullptr, mal1f, mar1f, hm, elm, erm, NM);
    aggr4_kernel<4, 6, 256><<<gA2m, 256, 0, stream>>>(hm, elm, erm, off_m, csr_m, gm, NM, 0.01f);
    colstats_kernel<<<64, 256, 0, stream>>>(gm, cb3, cb3 + 512, NM);

    // ---- mesh GAT layer 2 ----
    gemm_kernel<256, 96, 3, 5, true><<<gTm, 256, 0, stream>>>(
        gm, mW2f, cb3, mg1_gf, mg1_bf, mg1_af, mal2f, mar2f, hm, elm, erm, NM);
    aggr4_kernel<3, 5, 96><<<gA2m, 256, 0, stream>>>(hm, elm, erm, off_m, csr_m, gm, NM, 0.01f);
    colstats_kernel<<<64, 96, 0, stream>>>(gm, cb4, cb4 + 512, NM);

    // ---- mesh GAT layer 3 ----
    gemm_kernel<96, 64, 2, 5, true><<<gTm, 256, 0, stream>>>(
        gm, mW3f, cb4, mg2_gf, mg2_bf, mg2_af, mal3f, mar3f, hm, elm, erm, NM);
    aggr_mean_kernel<<<gM4, 256, 0, stream>>>(hm, elm, erm, off_m, csr_m, nullptr,
                                              msum, nullptr, NM);
    final_kernel<<<1, 64, 0, stream>>>(msum, mclsf, d_out, flag, NM);

    (void)n_in; (void)out_size; (void)ws_size;
}

// Round 15
// 830.058 us; speedup vs baseline: 1.0585x; 1.0585x over previous
//
#include <hip/hip_runtime.h>

typedef unsigned short ushort;
typedef unsigned int uint;
typedef __attribute__((ext_vector_type(8))) short short8;
typedef __attribute__((ext_vector_type(4))) float float4v;

#define DEV __device__ __forceinline__

DEV float b2f(ushort u) {
    union { uint i; float f; } v; v.i = ((uint)u) << 16; return v.f;
}
DEV ushort f2b(float f) {
    union { float f; uint i; } v; v.f = f;
    uint x = v.i;
    uint r = x + 0x7fffu + ((x >> 16) & 1u);
    return (ushort)(r >> 16);
}
DEV float leaky(float x, float s) { return x >= 0.f ? x : s * x; }

// ---------------- convert (+local sniff, +zero slice, +flag write) ----------------
struct ConvArgs {
    const void* s[37];
    float* d[37];
    int n[37];
};

__global__ __launch_bounds__(256) void convert_kernel(ConvArgs a, const ushort* __restrict__ x0,
                                                      int* __restrict__ flag) {
    __shared__ int sfp32;
    int tid = threadIdx.x;
    if (tid < 64) {
        int cnt = 0;
        for (int j = 0; j < 8; j++) {
            ushort u = x0[(tid * 8 + j) * 2];
            int e = (u >> 7) & 0xFF;
            if (e >= 100 && e <= 140) cnt++;
        }
#pragma unroll
        for (int m = 1; m < 64; m <<= 1) cnt += __shfl_xor(cnt, m, 64);
        if (tid == 0) sfp32 = (cnt < 256) ? 1 : 0;
    }
    __syncthreads();
    bool fp32 = (sfp32 != 0);
    if (blockIdx.x == 0 && blockIdx.y == 0 && tid == 0) *flag = fp32 ? 1 : 0;

    int ai = blockIdx.y;
    int n = a.n[ai];
    const void* s = a.s[ai];
    float* d = a.d[ai];
    int stride = gridDim.x * blockDim.x;
    if (s == nullptr) {
        for (int i = blockIdx.x * blockDim.x + tid; i < n; i += stride) d[i] = 0.f;
    } else {
        for (int i = blockIdx.x * blockDim.x + tid; i < n; i += stride)
            d[i] = fp32 ? ((const float*)s)[i] : b2f(((const ushort*)s)[i]);
    }
}

// ---------------- CSR build (patch+mesh merged) ----------------
__global__ __launch_bounds__(256) void hist_both(const int* __restrict__ dstP, int* __restrict__ cntP, int EPc,
                                                 const int* __restrict__ dstM, int* __restrict__ cntM, int EMc,
                                                 int PB) {
    bool patch = (int)blockIdx.x < PB;
    const int* dst = patch ? dstP : dstM;
    int* cnt = patch ? cntP : cntM;
    int E = patch ? EPc : EMc;
    int nb = patch ? PB : gridDim.x - PB;
    int b = patch ? blockIdx.x : blockIdx.x - PB;
    int stride = nb * blockDim.x;
    for (int i = b * blockDim.x + threadIdx.x; i < E; i += stride)
        atomicAdd(&cnt[dst[i]], 1);
}

__global__ __launch_bounds__(256) void scan_both(const int* __restrict__ cntP, int* __restrict__ offP,
                                                 int* __restrict__ bsumP, int nP, int SBP,
                                                 const int* __restrict__ cntM, int* __restrict__ offM,
                                                 int* __restrict__ bsumM, int nM) {
    __shared__ int ls[256];
    bool patch = (int)blockIdx.x < SBP;
    const int* cnt = patch ? cntP : cntM;
    int* off = patch ? offP : offM;
    int* bsum = patch ? bsumP : bsumM;
    int n = patch ? nP : nM;
    int b = patch ? blockIdx.x : blockIdx.x - SBP;
    int t = threadIdx.x;
    int base = b * 2048 + t * 8;
    int v[8];
    int s = 0;
#pragma unroll
    for (int i = 0; i < 8; i++) {
        int idx = base + i;
        v[i] = idx < n ? cnt[idx] : 0;
        s += v[i];
    }
    ls[t] = s;
    __syncthreads();
#pragma unroll
    for (int d = 1; d < 256; d <<= 1) {
        int add = (t >= d) ? ls[t - d] : 0;
        __syncthreads();
        ls[t] += add;
        __syncthreads();
    }
    int run = ls[t] - s;
#pragma unroll
    for (int i = 0; i < 8; i++) {
        int idx = base + i;
        if (idx < n) off[idx] = run;
        run += v[i];
    }
    if (t == 255) bsum[b] = ls[255];
}

__global__ __launch_bounds__(256) void fixup_both(const int* __restrict__ bsumP, int* __restrict__ offP,
                                                  int nP, int SBP,
                                                  const int* __restrict__ bsumM, int* __restrict__ offM,
                                                  int nM, int SBM) {
    bool patch = (int)blockIdx.x < SBP;
    const int* bsum = patch ? bsumP : bsumM;
    int* off = patch ? offP : offM;
    int n = patch ? nP : nM;
    int nb = patch ? SBP : SBM;
    int b = patch ? blockIdx.x : blockIdx.x - SBP;
    int t = threadIdx.x;
    int base = 0;
    for (int i = 0; i < b; i++) base += bsum[i];
    int idx0 = b * 2048 + t * 8;
    if (base != 0) {
#pragma unroll
        for (int i = 0; i < 8; i++) {
            int idx = idx0 + i;
            if (idx < n) off[idx] += base;
        }
    }
    if (b == nb - 1 && t == 255) off[n] = base + bsum[b];
}

__global__ __launch_bounds__(256) void scatter_both(const int* __restrict__ srcP, const int* __restrict__ dstP,
                                                    const int* __restrict__ offP, int* __restrict__ curP,
                                                    int* __restrict__ csrP, int EPc,
                                                    const int* __restrict__ srcM, const int* __restrict__ dstM,
                                                    const int* __restrict__ offM, int* __restrict__ curM,
                                                    int* __restrict__ csrM, int EMc, int PB) {
    bool patch = (int)blockIdx.x < PB;
    const int* src = patch ? srcP : srcM;
    const int* dst = patch ? dstP : dstM;
    const int* off = patch ? offP : offM;
    int* cursor = patch ? curP : curM;
    int* csr = patch ? csrP : csrM;
    int E = patch ? EPc : EMc;
    int nb = patch ? PB : gridDim.x - PB;
    int b = patch ? blockIdx.x : blockIdx.x - PB;
    int stride = nb * blockDim.x;
    for (int i = b * blockDim.x + threadIdx.x; i < E; i += stride) {
        int d = dst[i];
        int pos = off[d] + atomicAdd(&cursor[d], 1);
        csr[pos] = src[i];
    }
}

// ---------------- layer-1: el/er only ----------------
__global__ __launch_bounds__(256) void proj1_elr_kernel(const float* __restrict__ x,
                                                        const float* __restrict__ W,
                                                        const float* __restrict__ al,
                                                        const float* __restrict__ ar,
                                                        float* __restrict__ el,
                                                        float* __restrict__ er, int Nn) {
    int t = threadIdx.x;
    int head = t >> 6, lane = t & 63;
    float wv[5];
#pragma unroll
    for (int k = 0; k < 5; k++) wv[k] = W[k * 256 + t];
    float alv = al[t];
    float arv = ar[t];
    int n0 = blockIdx.x * 4;
    int n1 = min(n0 + 4, Nn);
    for (int n = n0; n < n1; n++) {
        float acc = 0.f;
#pragma unroll
        for (int k = 0; k < 5; k++) acc += x[n * 5 + k] * wv[k];
        float pl = acc * alv, pr = acc * arv;
#pragma unroll
        for (int m = 1; m < 64; m <<= 1) {
            pl += __shfl_xor(pl, m, 64);
            pr += __shfl_xor(pr, m, 64);
        }
        if (lane == 0) { el[n * 4 + head] = pl; er[n * 4 + head] = pr; }
    }
}

// ---------------- patch layer-1 aggregation: outer-product, 3 dst per wave ----------------
__global__ __launch_bounds__(256, 4) void aggr1_fly_kernel(const float* __restrict__ x,
                                                           const float* __restrict__ W,
                                                           const float* __restrict__ el,
                                                           const float* __restrict__ er,
                                                           const int* __restrict__ off,
                                                           const int* __restrict__ csr,
                                                           float* __restrict__ out, int Nn) {
    int wid = threadIdx.x >> 6;
    int lane = threadIdx.x & 63;
    int grp = lane / 20;          // 0..3 (grp 3 idle for edge work)
    int gl = lane - grp * 20;
    int dbase = blockIdx.x * 12 + wid * 3;
    int d = dbase + grp;
    bool accl = (grp < 3) && (d < Nn);
    int dd = accl ? d : 0;
    int h_ = gl / 5, k_ = gl - h_ * 5;  // h_ 0..3, k_ 0..4
    int c0 = lane * 4;
    int myhead = lane >> 4;
    float w0[5], w1[5], w2[5], w3[5];
#pragma unroll
    for (int k = 0; k < 5; k++) {
        float4 wv = *(const float4*)(W + k * 256 + c0);
        w0[k] = wv.x; w1[k] = wv.y; w2[k] = wv.z; w3[k] = wv.w;
    }
    float erd = accl ? er[dd * 4 + h_] : 0.f;
    float acc = 0.f, sh = 0.f;
    int e = accl ? off[dd] : 0;
    int e1 = accl ? off[dd + 1] : 0;
#define A1_ACC(XV, EV)                                  \
    {                                                   \
        float e0_ = (EV) + erd;                         \
        e0_ = e0_ >= 0.f ? e0_ : 0.2f * e0_;            \
        float w_ = __expf(fminf(e0_, 80.f));            \
        acc += w_ * (XV);                               \
        sh += w_;                                       \
    }
    for (; e + 4 <= e1; e += 4) {
        int s0 = csr[e], s1 = csr[e + 1], s2 = csr[e + 2], s3 = csr[e + 3];
        float x0 = x[s0 * 5 + k_];
        float x1 = x[s1 * 5 + k_];
        float x2 = x[s2 * 5 + k_];
        float x3 = x[s3 * 5 + k_];
        float v0 = el[s0 * 4 + h_];
        float v1 = el[s1 * 4 + h_];
        float v2 = el[s2 * 4 + h_];
        float v3 = el[s3 * 4 + h_];
        A1_ACC(x0, v0) A1_ACC(x1, v1) A1_ACC(x2, v2) A1_ACC(x3, v3)
    }
    for (; e < e1; e++) {
        int s0 = csr[e];
        float x0 = x[s0 * 5 + k_];
        float v0 = el[s0 * 4 + h_];
        A1_ACC(x0, v0)
    }
#undef A1_ACC
    // epilogue: for each of the 3 dsts, broadcast acc[h][:] and project through W
#pragma unroll
    for (int g3 = 0; g3 < 3; g3++) {
        int dsto = dbase + g3;
        if (dsto >= Nn) break;  // wave-uniform
        float a_k[5];
#pragma unroll
        for (int k = 0; k < 5; k++) a_k[k] = __shfl(acc, g3 * 20 + myhead * 5 + k, 64);
        float s = __shfl(sh, g3 * 20 + myhead * 5, 64);
        float inv = 1.f / fmaxf(s, 1e-9f);
        float o0 = 0.f, o1 = 0.f, o2 = 0.f, o3 = 0.f;
#pragma unroll
        for (int k = 0; k < 5; k++) {
            o0 += a_k[k] * w0[k]; o1 += a_k[k] * w1[k];
            o2 += a_k[k] * w2[k]; o3 += a_k[k] * w3[k];
        }
        float4 o;
        o.x = leaky(o0 * inv, 0.01f);
        o.y = leaky(o1 * inv, 0.01f);
        o.z = leaky(o2 * inv, 0.01f);
        o.w = leaky(o3 * inv, 0.01f);
        *(float4*)(out + (size_t)dsto * 256 + c0) = o;
    }
}

// ---------------- gather aggregation: 2 dst/wave, 8 cols/lane (bf16 in, fp32 out) ----------------
template <int H, int LOGD, int HD>
__global__ __launch_bounds__(256, 4) void aggr4_kernel(const ushort* __restrict__ h,
                                                       const float* __restrict__ el,
                                                       const float* __restrict__ er,
                                                       const int* __restrict__ off,
                                                       const int* __restrict__ csr,
                                                       float* __restrict__ out, int Nn,
                                                       float oslope) {
    int wid = threadIdx.x >> 6;
    int lane = threadIdx.x & 63;
    int half = lane >> 5, hl = lane & 31;
    constexpr int NL = HD / 8;
    int d = blockIdx.x * 8 + wid * 2 + half;
    bool valid = (hl < NL) && (d < Nn);
    int dd = valid ? d : 0;
    int myhead = (hl * 8) >> LOGD;
    float erd = valid ? er[dd * H + myhead] : 0.f;
    float a0 = 0.f, a1 = 0.f, a2 = 0.f, a3 = 0.f;
    float a4 = 0.f, a5 = 0.f, a6 = 0.f, a7 = 0.f, s = 0.f;
    int e = valid ? off[dd] : 0;
    int e1 = valid ? off[dd + 1] : 0;
#define A8_ACC(EV, HR)                                      \
    {                                                       \
        float ev_ = (EV) + erd;                             \
        ev_ = ev_ >= 0.f ? ev_ : 0.2f * ev_;                \
        float w_ = __expf(fminf(ev_, 80.f));                \
        a0 += w_ * b2f((ushort)(HR).x);                     \
        a1 += w_ * b2f((ushort)((HR).x >> 16));             \
        a2 += w_ * b2f((ushort)(HR).y);                     \
        a3 += w_ * b2f((ushort)((HR).y >> 16));             \
        a4 += w_ * b2f((ushort)(HR).z);                     \
        a5 += w_ * b2f((ushort)((HR).z >> 16));             \
        a6 += w_ * b2f((ushort)(HR).w);                     \
        a7 += w_ * b2f((ushort)((HR).w >> 16));             \
        s += w_;                                            \
    }
#define A8_ACCM(OK, EV, HR)                                 \
    {                                                       \
        float ev_ = (EV) + erd;                             \
        ev_ = ev_ >= 0.f ? ev_ : 0.2f * ev_;                \
        float w_ = (OK) ? __expf(fminf(ev_, 80.f)) : 0.f;   \
        a0 += w_ * b2f((ushort)(HR).x);                     \
        a1 += w_ * b2f((ushort)((HR).x >> 16));             \
        a2 += w_ * b2f((ushort)(HR).y);                     \
        a3 += w_ * b2f((ushort)((HR).y >> 16));             \
        a4 += w_ * b2f((ushort)(HR).z);                     \
        a5 += w_ * b2f((ushort)((HR).z >> 16));             \
        a6 += w_ * b2f((ushort)(HR).w);                     \
        a7 += w_ * b2f((ushort)((HR).w >> 16));             \
        s += w_;                                            \
    }
    for (; e + 4 <= e1; e += 4) {
        int s0 = csr[e], s1 = csr[e + 1], s2 = csr[e + 2], s3 = csr[e + 3];
        float e0 = el[s0 * H + myhead];
        float e1v = el[s1 * H + myhead];
        float e2v = el[s2 * H + myhead];
        float e3v = el[s3 * H + myhead];
        uint4 h0 = *(const uint4*)(h + (size_t)s0 * HD + hl * 8);
        uint4 h1 = *(const uint4*)(h + (size_t)s1 * HD + hl * 8);
        uint4 h2 = *(const uint4*)(h + (size_t)s2 * HD + hl * 8);
        uint4 h3 = *(const uint4*)(h + (size_t)s3 * HD + hl * 8);
        A8_ACC(e0, h0) A8_ACC(e1v, h1) A8_ACC(e2v, h2) A8_ACC(e3v, h3)
    }
    if (e < e1) {
        bool k1 = e + 1 < e1, k2 = e + 2 < e1, k3 = e + 3 < e1;
        int s0 = csr[e];
        int s1 = csr[k1 ? e + 1 : e];
        int s2 = csr[k2 ? e + 2 : e];
        int s3 = csr[k3 ? e + 3 : e];
        float e0 = el[s0 * H + myhead];
        float e1v = el[s1 * H + myhead];
        float e2v = el[s2 * H + myhead];
        float e3v = el[s3 * H + myhead];
        uint4 h0 = *(const uint4*)(h + (size_t)s0 * HD + hl * 8);
        uint4 h1 = *(const uint4*)(h + (size_t)s1 * HD + hl * 8);
        uint4 h2 = *(const uint4*)(h + (size_t)s2 * HD + hl * 8);
        uint4 h3 = *(const uint4*)(h + (size_t)s3 * HD + hl * 8);
        A8_ACCM(true, e0, h0) A8_ACCM(k1, e1v, h1) A8_ACCM(k2, e2v, h2) A8_ACCM(k3, e3v, h3)
    }
#undef A8_ACC
#undef A8_ACCM
    if (valid) {
        float inv = 1.f / fmaxf(s, 1e-9f);
        float4 oa, ob;
        oa.x = leaky(a0 * inv, oslope);
        oa.y = leaky(a1 * inv, oslope);
        oa.z = leaky(a2 * inv, oslope);
        oa.w = leaky(a3 * inv, oslope);
        ob.x = leaky(a4 * inv, oslope);
        ob.y = leaky(a5 * inv, oslope);
        ob.z = leaky(a6 * inv, oslope);
        ob.w = leaky(a7 * inv, oslope);
        float* po = out + (size_t)dd * HD + hl * 8;
        *(float4*)(po) = oa;
        *(float4*)(po + 4) = ob;
    }
}

// final GAT layer: H=2, D=32, HD=64 — 2 dst/wave, scalarized U=8 (round-13 proven shape)
__global__ __launch_bounds__(256, 4) void aggr_mean_kernel(const ushort* __restrict__ h,
                                                           const float* __restrict__ el,
                                                           const float* __restrict__ er,
                                                           const int* __restrict__ off,
                                                           const int* __restrict__ csr,
                                                           const int* __restrict__ gid,
                                                           float* __restrict__ out_sum,
                                                           float* __restrict__ out_cnt,
                                                           int Nn) {
    int wid = threadIdx.x >> 6;
    int lane = threadIdx.x & 63;
    int half = lane >> 5;
    int hl = lane & 31;
    int d = blockIdx.x * 8 + wid * 2 + half;
    bool valid = d < Nn;
    int dd = valid ? d : 0;
    int head = hl >> 4;  // cols 2hl, 2hl+1; head1 when hl>=16
    float erd = er[dd * 2 + head];
    float a0 = 0.f, a1 = 0.f, s = 0.f;
    int e = valid ? off[dd] : 0;
    int e1 = valid ? off[dd + 1] : 0;
#define AM_ACC(Q, V)                                        \
    {                                                       \
        float ev_ = (head ? (Q).y : (Q).x) + erd;           \
        ev_ = ev_ >= 0.f ? ev_ : 0.2f * ev_;                \
        float w_ = __expf(fminf(ev_, 80.f));                \
        a0 += w_ * b2f((ushort)(V));                        \
        a1 += w_ * b2f((ushort)((V) >> 16));                \
        s += w_;                                            \
    }
#define AM_ACCM(OK, Q, V)                                   \
    {                                                       \
        float ev_ = (head ? (Q).y : (Q).x) + erd;           \
        ev_ = ev_ >= 0.f ? ev_ : 0.2f * ev_;                \
        float w_ = (OK) ? __expf(fminf(ev_, 80.f)) : 0.f;   \
        a0 += w_ * b2f((ushort)(V));                        \
        a1 += w_ * b2f((ushort)((V) >> 16));                \
        s += w_;                                            \
    }
    for (; e + 8 <= e1; e += 8) {
        int s0 = csr[e], s1 = csr[e + 1], s2 = csr[e + 2], s3 = csr[e + 3];
        int s4 = csr[e + 4], s5 = csr[e + 5], s6 = csr[e + 6], s7 = csr[e + 7];
        float2 q0 = *(const float2*)(el + s0 * 2);
        float2 q1 = *(const float2*)(el + s1 * 2);
        float2 q2 = *(const float2*)(el + s2 * 2);
        float2 q3 = *(const float2*)(el + s3 * 2);
        float2 q4 = *(const float2*)(el + s4 * 2);
        float2 q5 = *(const float2*)(el + s5 * 2);
        float2 q6 = *(const float2*)(el + s6 * 2);
        float2 q7 = *(const float2*)(el + s7 * 2);
        uint v0 = *(const uint*)(h + (size_t)s0 * 64 + hl * 2);
        uint v1 = *(const uint*)(h + (size_t)s1 * 64 + hl * 2);
        uint v2 = *(const uint*)(h + (size_t)s2 * 64 + hl * 2);
        uint v3 = *(const uint*)(h + (size_t)s3 * 64 + hl * 2);
        uint v4 = *(const uint*)(h + (size_t)s4 * 64 + hl * 2);
        uint v5 = *(const uint*)(h + (size_t)s5 * 64 + hl * 2);
        uint v6 = *(const uint*)(h + (size_t)s6 * 64 + hl * 2);
        uint v7 = *(const uint*)(h + (size_t)s7 * 64 + hl * 2);
        AM_ACC(q0, v0) AM_ACC(q1, v1) AM_ACC(q2, v2) AM_ACC(q3, v3)
        AM_ACC(q4, v4) AM_ACC(q5, v5) AM_ACC(q6, v6) AM_ACC(q7, v7)
    }
    if (e < e1) {
        bool k1 = e + 1 < e1, k2 = e + 2 < e1, k3 = e + 3 < e1;
        bool k4 = e + 4 < e1, k5 = e + 5 < e1, k6 = e + 6 < e1, k7 = e + 7 < e1;
        int s0 = csr[e];
        int s1 = csr[k1 ? e + 1 : e];
        int s2 = csr[k2 ? e + 2 : e];
        int s3 = csr[k3 ? e + 3 : e];
        int s4 = csr[k4 ? e + 4 : e];
        int s5 = csr[k5 ? e + 5 : e];
        int s6 = csr[k6 ? e + 6 : e];
        int s7 = csr[k7 ? e + 7 : e];
        float2 q0 = *(const float2*)(el + s0 * 2);
        float2 q1 = *(const float2*)(el + s1 * 2);
        float2 q2 = *(const float2*)(el + s2 * 2);
        float2 q3 = *(const float2*)(el + s3 * 2);
        float2 q4 = *(const float2*)(el + s4 * 2);
        float2 q5 = *(const float2*)(el + s5 * 2);
        float2 q6 = *(const float2*)(el + s6 * 2);
        float2 q7 = *(const float2*)(el + s7 * 2);
        uint v0 = *(const uint*)(h + (size_t)s0 * 64 + hl * 2);
        uint v1 = *(const uint*)(h + (size_t)s1 * 64 + hl * 2);
        uint v2 = *(const uint*)(h + (size_t)s2 * 64 + hl * 2);
        uint v3 = *(const uint*)(h + (size_t)s3 * 64 + hl * 2);
        uint v4 = *(const uint*)(h + (size_t)s4 * 64 + hl * 2);
        uint v5 = *(const uint*)(h + (size_t)s5 * 64 + hl * 2);
        uint v6 = *(const uint*)(h + (size_t)s6 * 64 + hl * 2);
        uint v7 = *(const uint*)(h + (size_t)s7 * 64 + hl * 2);
        AM_ACCM(true, q0, v0) AM_ACCM(k1, q1, v1) AM_ACCM(k2, q2, v2) AM_ACCM(k3, q3, v3)
        AM_ACCM(k4, q4, v4) AM_ACCM(k5, q5, v5) AM_ACCM(k6, q6, v6) AM_ACCM(k7, q7, v7)
    }
#undef AM_ACC
#undef AM_ACCM
    float inv = 1.f / fmaxf(s, 1e-9f);
    float y0 = a0 * inv, y1 = a1 * inv;
    // head-mean: col c pairs with c+32 -> lane hl+16 within same half
    float p0 = __shfl(y0, lane + 16, 64);
    float p1 = __shfl(y1, lane + 16, 64);
    if (valid && hl < 16) {
        float hm0 = 0.5f * (y0 + p0);
        float hm1 = 0.5f * (y1 + p1);
        int base = gid ? gid[d] * 32 : 0;
        atomicAdd(&out_sum[base + 2 * hl], hm0);
        atomicAdd(&out_sum[base + 2 * hl + 1], hm1);
        if (hl == 0 && out_cnt) atomicAdd(&out_cnt[gid[d]], 1.0f);
    }
}

// ---------------- GraphNorm column stats (fp32 input, 8-row unroll, scalarized) ----------------
__global__ void colstats_kernel(const float* __restrict__ x,
                                float* __restrict__ sum,
                                float* __restrict__ sumsq, int Nn) {
    int C = blockDim.x, c = threadIdx.x;
    int nb = gridDim.x;
    int chunk = (Nn + nb - 1) / nb;
    int r0 = blockIdx.x * chunk;
    int r1 = min(r0 + chunk, Nn);
    float ls = 0.f, lq = 0.f;
    int r = r0;
    for (; r + 8 <= r1; r += 8) {
        const float* p = x + (size_t)r * C + c;
        float v0 = p[0];
        float v1 = p[C];
        float v2 = p[2 * C];
        float v3 = p[3 * C];
        float v4 = p[4 * C];
        float v5 = p[5 * C];
        float v6 = p[6 * C];
        float v7 = p[7 * C];
        ls += ((v0 + v1) + (v2 + v3)) + ((v4 + v5) + (v6 + v7));
        lq += ((v0 * v0 + v1 * v1) + (v2 * v2 + v3 * v3)) +
              ((v4 * v4 + v5 * v5) + (v6 * v6 + v7 * v7));
    }
    for (; r < r1; r++) {
        float v = x[(size_t)r * C + c];
        ls += v; lq += v * v;
    }
    atomicAdd(&sum[c], ls);
    atomicAdd(&sumsq[c], lq);
}

// GraphNorm apply for readout: writes d_out (per flag) + fp32 mesh input
__global__ void gnorm_apply_ro_kernel(const float* __restrict__ x,
                                      const float* __restrict__ sum,
                                      const float* __restrict__ sumsq,
                                      const float* __restrict__ g,
                                      const float* __restrict__ b,
                                      const float* __restrict__ a,
                                      void* __restrict__ doutv,
                                      const int* __restrict__ flag,
                                      float* __restrict__ rof, int Nn) {
    int c = threadIdx.x;  // C = 32
    float invn = 1.f / (float)Nn;
    float mu = sum[c] * invn, ex2 = sumsq[c] * invn;
    float av = a[c];
    float var = ex2 - 2.f * av * mu * mu + av * av * mu * mu;
    float sc = g[c] * rsqrtf(var + 1e-5f);
    float sh = b[c] - sc * av * mu;
    bool fp32 = (*flag != 0);
    for (int r = blockIdx.x; r < Nn; r += gridDim.x) {
        int i = r * 32 + c;
        float v = x[i] * sc + sh;
        rof[i] = v;
        if (fp32) ((float*)doutv)[15 + i] = v;
        else      ((ushort*)doutv)[15 + i] = f2b(v);
    }
}

// ---------------- readout: segment-mean @ pcls + leaky (fp32 out) ----------------
__global__ __launch_bounds__(256) void readout_kernel(const float* __restrict__ ro_sum,
                                                      const float* __restrict__ ro_cnt,
                                                      const float* __restrict__ pcls,
                                                      float* __restrict__ ro_lin, int NGc) {
    int idx = blockIdx.x * blockDim.x + threadIdx.x;
    int g = idx >> 5, c = idx & 31;
    if (g >= NGc) return;
    float inv = 1.f / fmaxf(ro_cnt[g], 1.f);
    float acc = 0.f;
#pragma unroll
    for (int k = 0; k < 32; k++) acc += ro_sum[g * 32 + k] * inv * pcls[k * 32 + c];
    ro_lin[g * 32 + c] = leaky(acc, 0.01f);
}

// ---------------- MFMA GEMM: C(bf16) = gnorm(A:fp32) @ B, fused gnfin + elr ----------------
template <int K, int N, int H, int LOGD, bool GN>
__global__ __launch_bounds__(256) void gemm_kernel(const float* __restrict__ A,
                                                   const float* __restrict__ B,
                                                   const float* __restrict__ csum,
                                                   const float* __restrict__ g,
                                                   const float* __restrict__ gb,
                                                   const float* __restrict__ ga,
                                                   const float* __restrict__ al,
                                                   const float* __restrict__ ar,
                                                   ushort* __restrict__ C,
                                                   float* __restrict__ el,
                                                   float* __restrict__ er, int M) {
    constexpr int NT = N / 16;
    constexpr int AROW = 40;
    __shared__ __align__(16) ushort Alds[64 * AROW];
    __shared__ __align__(16) ushort Blds[32 * N];  // swizzled [k/8][n][k%8]
    __shared__ float ScL[256], ShL[256];
    int tid = threadIdx.x;
    int w = tid >> 6, lane = tid & 63, q = lane >> 4, l16 = lane & 15;
    int m0 = blockIdx.x * 64;
    if (GN && tid < K) {
        float invn = 1.f / (float)M;
        float mu = csum[tid] * invn, ex2 = csum[512 + tid] * invn;
        float av = ga[tid];
        float var = ex2 - 2.f * av * mu * mu + av * av * mu * mu;
        float sc = g[tid] * rsqrtf(var + 1e-5f);
        ScL[tid] = sc;
        ShL[tid] = gb[tid] - sc * av * mu;
    }
    float4v acc[NT];
#pragma unroll
    for (int nt = 0; nt < NT; nt++) acc[nt] = (float4v){0.f, 0.f, 0.f, 0.f};

    for (int kc = 0; kc < K; kc += 32) {
        __syncthreads();
        {
#pragma unroll
            for (int it = 0; it < 2; it++) {
                int idx = it * 256 + tid;
                int r = idx >> 3;
                int c4 = (idx & 7) * 4;
                int gr = m0 + r;
                float4 av = {0.f, 0.f, 0.f, 0.f};
                if (gr < M) av = *(const float4*)(A + (size_t)gr * K + kc + c4);
                if (GN) {
                    av.x = av.x * ScL[kc + c4] + ShL[kc + c4];
                    av.y = av.y * ScL[kc + c4 + 1] + ShL[kc + c4 + 1];
                    av.z = av.z * ScL[kc + c4 + 2] + ShL[kc + c4 + 2];
                    av.w = av.w * ScL[kc + c4 + 3] + ShL[kc + c4 + 3];
                }
                uint2 pk;
                pk.x = (uint)f2b(av.x) | ((uint)f2b(av.y) << 16);
                pk.y = (uint)f2b(av.z) | ((uint)f2b(av.w) << 16);
                *(uint2*)(&Alds[r * AROW + c4]) = pk;
            }
        }
        {
            constexpr int PAIRS = 16 * N;
#pragma unroll
            for (int p0 = 0; p0 < PAIRS; p0 += 256) {
                int p = p0 + tid;
                int k_ = p / (N / 2);
                int n0 = (p % (N / 2)) * 2;
                float2 bv = *(const float2*)(B + (size_t)(kc + k_) * N + n0);
                int base = (((k_ >> 3) * N + n0) << 3) + (k_ & 7);
                Blds[base] = f2b(bv.x);
                Blds[base + 8] = f2b(bv.y);
            }
        }
        __syncthreads();
        short8 a = *(const short8*)(&Alds[(w * 16 + l16) * AROW + q * 8]);
#pragma unroll
        for (int nt = 0; nt < NT; nt++) {
            short8 b = *(const short8*)(&Blds[(q * N + nt * 16 + l16) * 8]);
            acc[nt] = __builtin_amdgcn_mfma_f32_16x16x32_bf16(a, b, acc[nt], 0, 0, 0);
        }
    }
    // store C (bf16) + fused el/er
    float pel[4][H], per[4][H];
#pragma unroll
    for (int i = 0; i < 4; i++)
#pragma unroll
        for (int hh = 0; hh < H; hh++) { pel[i][hh] = 0.f; per[i][hh] = 0.f; }
#pragma unroll
    for (int nt = 0; nt < NT; nt++) {
        int col = nt * 16 + l16;
        float alc = al[col], arc = ar[col];
        constexpr int HSH = LOGD - 4;
        int hh = nt >> HSH;
#pragma unroll
        for (int i = 0; i < 4; i++) {
            int row = m0 + w * 16 + q * 4 + i;
            float v = acc[nt][i];
            if (row < M) C[(size_t)row * N + col] = f2b(v);
            pel[i][hh] += v * alc;
            per[i][hh] += v * arc;
        }
    }
#pragma unroll
    for (int i = 0; i < 4; i++) {
#pragma unroll
        for (int hh = 0; hh < H; hh++) {
            float vl = pel[i][hh], vr = per[i][hh];
#pragma unroll
            for (int m = 1; m < 16; m <<= 1) {
                vl += __shfl_xor(vl, m, 64);
                vr += __shfl_xor(vr, m, 64);
            }
            if (l16 == 0) {
                int row = m0 + w * 16 + q * 4 + i;
                if (row < M) { el[row * H + hh] = vl; er[row * H + hh] = vr; }
            }
        }
    }
}

// ---------------- final: node-mean @ mcls ----------------
__global__ __launch_bounds__(64) void final_kernel(const float* __restrict__ msum,
                                                   const float* __restrict__ mcls,
                                                   void* __restrict__ doutv,
                                                   const int* __restrict__ flag, int Nm) {
    int t = threadIdx.x;
    if (t < 15) {
        float inv = 1.f / (float)Nm;
        float acc = 0.f;
#pragma unroll
        for (int c = 0; c < 32; c++) acc += msum[c] * inv * mcls[c * 15 + t];
        if (*flag) ((float*)doutv)[t] = acc;
        else       ((ushort*)doutv)[t] = f2b(acc);
    }
}

extern "C" void kernel_launch(void* const* d_in, const int* in_sizes, int n_in,
                              void* d_out, int out_size, void* d_ws, size_t ws_size,
                              hipStream_t stream) {
    const int NP = 100000, NG = 2000, EP = 800000, NM = 2000, EM = 32000;

    const int* patch_src = (const int*)d_in[1];
    const int* patch_dst = (const int*)d_in[2];
    const int* patch_gid = (const int*)d_in[3];
    const int* mesh_src = (const int*)d_in[4];
    const int* mesh_dst = (const int*)d_in[5];

    char* p = (char*)d_ws;
    auto alloc = [&](size_t bytes) -> char* {
        char* r = p;
        p += (bytes + 255) & ~(size_t)255;
        return r;
    };
    char* zbase = p;
    int* cnt_p = (int*)alloc((size_t)NP * 4);
    int* cursor_p = (int*)alloc((size_t)NP * 4);
    int* cnt_m = (int*)alloc((size_t)NM * 4);
    int* cursor_m = (int*)alloc((size_t)NM * 4);
    float* ro_sum = (float*)alloc((size_t)NG * 32 * 4);
    float* ro_cnt = (float*)alloc((size_t)NG * 4);
    float* msum = (float*)alloc(32 * 4);
    float* colbuf = (float*)alloc(6 * 1024 * 4);
    size_t zbytes = (size_t)(p - zbase);
    int* flag = (int*)alloc(256);
    int* off_p = (int*)alloc((size_t)(NP + 1) * 4);
    int* off_m = (int*)alloc((size_t)(NM + 1) * 4);
    int* bsum_p = (int*)alloc(64 * 4);
    int* bsum_m = (int*)alloc(16 * 4);
    int* csr_p = (int*)alloc((size_t)EP * 4);
    int* csr_m = (int*)alloc((size_t)EM * 4);
    float* el = (float*)alloc((size_t)NP * 4 * 4);
    float* er = (float*)alloc((size_t)NP * 4 * 4);
    ushort* hbuf = (ushort*)alloc((size_t)NP * 256 * 2);   // bf16 gather buffer
    float* gbuf = (float*)alloc((size_t)NP * 256 * 4);     // fp32 aggr output
    ushort* hm = (ushort*)alloc((size_t)NM * 256 * 2);
    float* gm = (float*)alloc((size_t)NM * 256 * 4);
    float* elm = (float*)alloc((size_t)NM * 4 * 4);
    float* erm = (float*)alloc((size_t)NM * 4 * 4);
    float* ro_lin = (float*)alloc((size_t)NG * 32 * 4);
    float* ro_f = (float*)alloc((size_t)NG * 32 * 4);

    ConvArgs ca;
    float* convp[36];
    int conv_idx[36];
    conv_idx[0] = 0;
    for (int i = 1; i < 36; i++) conv_idx[i] = 5 + i;
    for (int j = 0; j < 36; j++) {
        int ii = conv_idx[j];
        int n = in_sizes[ii];
        float* dd = (float*)alloc((size_t)n * 4);
        ca.s[j] = d_in[ii];
        ca.d[j] = dd;
        ca.n[j] = n;
        convp[j] = dd;
    }
    ca.s[36] = nullptr;
    ca.d[36] = (float*)zbase;
    ca.n[36] = (int)(zbytes / 4);

    const float* xf = convp[0];
    const float *pW1f = convp[1], *pal1f = convp[2], *par1f = convp[3];
    const float *pg1_gf = convp[4], *pg1_bf = convp[5], *pg1_af = convp[6];
    const float *pW2f = convp[7], *pal2f = convp[8], *par2f = convp[9];
    const float *pg2_gf = convp[10], *pg2_bf = convp[11], *pg2_af = convp[12];
    const float *pW3f = convp[13], *pal3f = convp[14], *par3f = convp[15];
    const float* pclsf = convp[16];
    const float *rn_gf = convp[17], *rn_bf2 = convp[18], *rn_af = convp[19];
    const float *mW1f = convp[20], *mal1f = convp[21], *mar1f = convp[22];
    const float *mg1_gf = convp[23], *mg1_bf = convp[24], *mg1_af = convp[25];
    const float *mW2f = convp[26], *mal2f = convp[27], *mar2f = convp[28];
    const float *mg2_gf = convp[29], *mg2_bf = convp[30], *mg2_af = convp[31];
    const float *mW3f = convp[32], *mal3f = convp[33], *mar3f = convp[34];
    const float* mclsf = convp[35];

    convert_kernel<<<dim3(16, 37), 256, 0, stream>>>(ca, (const ushort*)d_in[0], flag);

    const int SBP = (NP + 2047) / 2048, SBM = (NM + 2047) / 2048;
    hist_both<<<512 + 64, 256, 0, stream>>>(patch_dst, cnt_p, EP, mesh_dst, cnt_m, EM, 512);
    scan_both<<<SBP + SBM, 256, 0, stream>>>(cnt_p, off_p, bsum_p, NP, SBP, cnt_m, off_m, bsum_m, NM);
    fixup_both<<<SBP + SBM, 256, 0, stream>>>(bsum_p, off_p, NP, SBP, bsum_m, off_m, NM, SBM);
    scatter_both<<<512 + 64, 256, 0, stream>>>(patch_src, patch_dst, off_p, cursor_p, csr_p, EP,
                                               mesh_src, mesh_dst, off_m, cursor_m, csr_m, EM, 512);

    int gP = (NP + 3) / 4;
    int gP12 = (NP + 11) / 12;
    int gA2 = (NP + 7) / 8, gA2m = (NM + 7) / 8;
    int gP2 = (NP + 7) / 8, gM2 = (NM + 7) / 8;
    int gT = (NP + 63) / 64, gTm = (NM + 63) / 64;
    float* cb0 = colbuf + 0 * 1024;
    float* cb1 = colbuf + 1 * 1024;
    float* cb2 = colbuf + 2 * 1024;
    float* cb3 = colbuf + 3 * 1024;
    float* cb4 = colbuf + 4 * 1024;

    // ---- patch GAT layer 1 ----
    proj1_elr_kernel<<<gP, 256, 0, stream>>>(xf, pW1f, pal1f, par1f, el, er, NP);
    aggr1_fly_kernel<<<gP12, 256, 0, stream>>>(xf, pW1f, el, er, off_p, csr_p, gbuf, NP);
    colstats_kernel<<<512, 256, 0, stream>>>(gbuf, cb0, cb0 + 512, NP);

    // ---- patch GAT layer 2 ----
    gemm_kernel<256, 192, 3, 6, true><<<gT, 256, 0, stream>>>(
        gbuf, pW2f, cb0, pg1_gf, pg1_bf, pg1_af, pal2f, par2f, hbuf, el, er, NP);
    aggr4_kernel<3, 6, 192><<<gA2, 256, 0, stream>>>(hbuf, el, er, off_p, csr_p, gbuf, NP, 0.01f);
    colstats_kernel<<<512, 192, 0, stream>>>(gbuf, cb1, cb1 + 512, NP);

    // ---- patch GAT layer 3 + readout ----
    gemm_kernel<192, 64, 2, 5, true><<<gT, 256, 0, stream>>>(
        gbuf, pW3f, cb1, pg2_gf, pg2_bf, pg2_af, pal3f, par3f, hbuf, el, er, NP);
    aggr_mean_kernel<<<gP2, 256, 0, stream>>>(hbuf, el, er, off_p, csr_p, patch_gid,
                                              ro_sum, ro_cnt, NP);

    readout_kernel<<<(NG * 32 + 255) / 256, 256, 0, stream>>>(ro_sum, ro_cnt, pclsf, ro_lin, NG);
    colstats_kernel<<<64, 32, 0, stream>>>(ro_lin, cb2, cb2 + 512, NG);
    gnorm_apply_ro_kernel<<<64, 32, 0, stream>>>(ro_lin, cb2, cb2 + 512, rn_gf, rn_bf2, rn_af,
                                                 d_out, flag, ro_f, NG);

    // ---- mesh GAT layer 1 ----
    gemm_kernel<32, 256, 4, 6, false><<<gTm, 256, 0, stream>>>(
        ro_f, mW1f, nullptr, nullptr, nullptr, nullptr, mal1f, mar1f, hm, elm, erm, NM);
    aggr4_kernel<4, 6, 256><<<gA2m, 256, 0, stream>>>(hm, elm, erm, off_m, csr_m, gm, NM, 0.01f);
    colstats_kernel<<<64, 256, 0, stream>>>(gm, cb3, cb3 + 512, NM);

    // ---- mesh GAT layer 2 ----
    gemm_kernel<256, 96, 3, 5, true><<<gTm, 256, 0, stream>>>(
        gm, mW2f, cb3, mg1_gf, mg1_bf, mg1_af, mal2f, mar2f, hm, elm, erm, NM);
    aggr4_kernel<3, 5, 96><<<gA2m, 256, 0, stream>>>(hm, elm, erm, off_m, csr_m, gm, NM, 0.01f);
    colstats_kernel<<<64, 96, 0, stream>>>(gm, cb4, cb4 + 512, NM);

    // ---- mesh GAT layer 3 ----
    gemm_kernel<96, 64, 2, 5, true><<<gTm, 256, 0, stream>>>(
        gm, mW3f, cb4, mg2_gf, mg2_bf, mg2_af, mal3f, mar3f, hm, elm, erm, NM);
    aggr_mean_kernel<<<gM2, 256, 0, stream>>>(hm, elm, erm, off_m, csr_m, nullptr,
                                              msum, nullptr, NM);
    final_kernel<<<1, 64, 0, stream>>>(msum, mclsf, d_out, flag, NM);

    (void)n_in; (void)out_size; (void)ws_size;
}

// Round 16
// 703.237 us; speedup vs baseline: 1.2493x; 1.1803x over previous
//
#include <hip/hip_runtime.h>

typedef unsigned short ushort;
typedef unsigned int uint;
typedef __attribute__((ext_vector_type(8))) short short8;
typedef __attribute__((ext_vector_type(4))) float float4v;

#define DEV __device__ __forceinline__

DEV float b2f(ushort u) {
    union { uint i; float f; } v; v.i = ((uint)u) << 16; return v.f;
}
DEV ushort f2b(float f) {
    union { float f; uint i; } v; v.f = f;
    uint x = v.i;
    uint r = x + 0x7fffu + ((x >> 16) & 1u);
    return (ushort)(r >> 16);
}
DEV float leaky(float x, float s) { return x >= 0.f ? x : s * x; }

// ---------------- convert (+local sniff, +zero slice, +flag write) ----------------
struct ConvArgs {
    const void* s[37];
    float* d[37];
    int n[37];
};

__global__ __launch_bounds__(256) void convert_kernel(ConvArgs a, const ushort* __restrict__ x0,
                                                      int* __restrict__ flag) {
    __shared__ int sfp32;
    int tid = threadIdx.x;
    if (tid < 64) {
        int cnt = 0;
        for (int j = 0; j < 8; j++) {
            ushort u = x0[(tid * 8 + j) * 2];
            int e = (u >> 7) & 0xFF;
            if (e >= 100 && e <= 140) cnt++;
        }
#pragma unroll
        for (int m = 1; m < 64; m <<= 1) cnt += __shfl_xor(cnt, m, 64);
        if (tid == 0) sfp32 = (cnt < 256) ? 1 : 0;
    }
    __syncthreads();
    bool fp32 = (sfp32 != 0);
    if (blockIdx.x == 0 && blockIdx.y == 0 && tid == 0) *flag = fp32 ? 1 : 0;

    int ai = blockIdx.y;
    int n = a.n[ai];
    const void* s = a.s[ai];
    float* d = a.d[ai];
    int stride = gridDim.x * blockDim.x;
    if (s == nullptr) {
        for (int i = blockIdx.x * blockDim.x + tid; i < n; i += stride) d[i] = 0.f;
    } else {
        for (int i = blockIdx.x * blockDim.x + tid; i < n; i += stride)
            d[i] = fp32 ? ((const float*)s)[i] : b2f(((const ushort*)s)[i]);
    }
}

// ---------------- CSR build (patch+mesh merged) ----------------
__global__ __launch_bounds__(256) void hist_both(const int* __restrict__ dstP, int* __restrict__ cntP, int EPc,
                                                 const int* __restrict__ dstM, int* __restrict__ cntM, int EMc,
                                                 int PB) {
    bool patch = (int)blockIdx.x < PB;
    const int* dst = patch ? dstP : dstM;
    int* cnt = patch ? cntP : cntM;
    int E = patch ? EPc : EMc;
    int nb = patch ? PB : gridDim.x - PB;
    int b = patch ? blockIdx.x : blockIdx.x - PB;
    int stride = nb * blockDim.x;
    for (int i = b * blockDim.x + threadIdx.x; i < E; i += stride)
        atomicAdd(&cnt[dst[i]], 1);
}

__global__ __launch_bounds__(256) void scan_both(const int* __restrict__ cntP, int* __restrict__ offP,
                                                 int* __restrict__ bsumP, int nP, int SBP,
                                                 const int* __restrict__ cntM, int* __restrict__ offM,
                                                 int* __restrict__ bsumM, int nM) {
    __shared__ int ls[256];
    bool patch = (int)blockIdx.x < SBP;
    const int* cnt = patch ? cntP : cntM;
    int* off = patch ? offP : offM;
    int* bsum = patch ? bsumP : bsumM;
    int n = patch ? nP : nM;
    int b = patch ? blockIdx.x : blockIdx.x - SBP;
    int t = threadIdx.x;
    int base = b * 2048 + t * 8;
    int v[8];
    int s = 0;
#pragma unroll
    for (int i = 0; i < 8; i++) {
        int idx = base + i;
        v[i] = idx < n ? cnt[idx] : 0;
        s += v[i];
    }
    ls[t] = s;
    __syncthreads();
#pragma unroll
    for (int d = 1; d < 256; d <<= 1) {
        int add = (t >= d) ? ls[t - d] : 0;
        __syncthreads();
        ls[t] += add;
        __syncthreads();
    }
    int run = ls[t] - s;
#pragma unroll
    for (int i = 0; i < 8; i++) {
        int idx = base + i;
        if (idx < n) off[idx] = run;
        run += v[i];
    }
    if (t == 255) bsum[b] = ls[255];
}

__global__ __launch_bounds__(256) void fixup_both(const int* __restrict__ bsumP, int* __restrict__ offP,
                                                  int nP, int SBP,
                                                  const int* __restrict__ bsumM, int* __restrict__ offM,
                                                  int nM, int SBM) {
    bool patch = (int)blockIdx.x < SBP;
    const int* bsum = patch ? bsumP : bsumM;
    int* off = patch ? offP : offM;
    int n = patch ? nP : nM;
    int nb = patch ? SBP : SBM;
    int b = patch ? blockIdx.x : blockIdx.x - SBP;
    int t = threadIdx.x;
    int base = 0;
    for (int i = 0; i < b; i++) base += bsum[i];
    int idx0 = b * 2048 + t * 8;
    if (base != 0) {
#pragma unroll
        for (int i = 0; i < 8; i++) {
            int idx = idx0 + i;
            if (idx < n) off[idx] += base;
        }
    }
    if (b == nb - 1 && t == 255) off[n] = base + bsum[b];
}

__global__ __launch_bounds__(256) void scatter_both(const int* __restrict__ srcP, const int* __restrict__ dstP,
                                                    const int* __restrict__ offP, int* __restrict__ curP,
                                                    int* __restrict__ csrP, int EPc,
                                                    const int* __restrict__ srcM, const int* __restrict__ dstM,
                                                    const int* __restrict__ offM, int* __restrict__ curM,
                                                    int* __restrict__ csrM, int EMc, int PB) {
    bool patch = (int)blockIdx.x < PB;
    const int* src = patch ? srcP : srcM;
    const int* dst = patch ? dstP : dstM;
    const int* off = patch ? offP : offM;
    int* cursor = patch ? curP : curM;
    int* csr = patch ? csrP : csrM;
    int E = patch ? EPc : EMc;
    int nb = patch ? PB : gridDim.x - PB;
    int b = patch ? blockIdx.x : blockIdx.x - PB;
    int stride = nb * blockDim.x;
    for (int i = b * blockDim.x + threadIdx.x; i < E; i += stride) {
        int d = dst[i];
        int pos = off[d] + atomicAdd(&cursor[d], 1);
        csr[pos] = src[i];
    }
}

// ---------------- layer-1: el/er only ----------------
__global__ __launch_bounds__(256) void proj1_elr_kernel(const float* __restrict__ x,
                                                        const float* __restrict__ W,
                                                        const float* __restrict__ al,
                                                        const float* __restrict__ ar,
                                                        float* __restrict__ el,
                                                        float* __restrict__ er, int Nn) {
    int t = threadIdx.x;
    int head = t >> 6, lane = t & 63;
    float wv[5];
#pragma unroll
    for (int k = 0; k < 5; k++) wv[k] = W[k * 256 + t];
    float alv = al[t];
    float arv = ar[t];
    int n0 = blockIdx.x * 4;
    int n1 = min(n0 + 4, Nn);
    for (int n = n0; n < n1; n++) {
        float acc = 0.f;
#pragma unroll
        for (int k = 0; k < 5; k++) acc += x[n * 5 + k] * wv[k];
        float pl = acc * alv, pr = acc * arv;
#pragma unroll
        for (int m = 1; m < 64; m <<= 1) {
            pl += __shfl_xor(pl, m, 64);
            pr += __shfl_xor(pr, m, 64);
        }
        if (lane == 0) { el[n * 4 + head] = pl; er[n * 4 + head] = pr; }
    }
}

// ---------------- patch layer-1 aggregation: outer-product, 3 dst per wave ----------------
__global__ __launch_bounds__(256, 4) void aggr1_fly_kernel(const float* __restrict__ x,
                                                           const float* __restrict__ W,
                                                           const float* __restrict__ el,
                                                           const float* __restrict__ er,
                                                           const int* __restrict__ off,
                                                           const int* __restrict__ csr,
                                                           float* __restrict__ out, int Nn) {
    int wid = threadIdx.x >> 6;
    int lane = threadIdx.x & 63;
    int grp = lane / 20;          // 0..3 (grp 3 idle for edge work)
    int gl = lane - grp * 20;
    int dbase = blockIdx.x * 12 + wid * 3;
    int d = dbase + grp;
    bool accl = (grp < 3) && (d < Nn);
    int dd = accl ? d : 0;
    int h_ = gl / 5, k_ = gl - h_ * 5;  // h_ 0..3, k_ 0..4
    int c0 = lane * 4;
    int myhead = lane >> 4;
    float w0[5], w1[5], w2[5], w3[5];
#pragma unroll
    for (int k = 0; k < 5; k++) {
        float4 wv = *(const float4*)(W + k * 256 + c0);
        w0[k] = wv.x; w1[k] = wv.y; w2[k] = wv.z; w3[k] = wv.w;
    }
    float erd = accl ? er[dd * 4 + h_] : 0.f;
    float acc = 0.f, sh = 0.f;
    int e = accl ? off[dd] : 0;
    int e1 = accl ? off[dd + 1] : 0;
#define A1_ACC(XV, EV)                                  \
    {                                                   \
        float e0_ = (EV) + erd;                         \
        e0_ = e0_ >= 0.f ? e0_ : 0.2f * e0_;            \
        float w_ = __expf(fminf(e0_, 80.f));            \
        acc += w_ * (XV);                               \
        sh += w_;                                       \
    }
    for (; e + 4 <= e1; e += 4) {
        int s0 = csr[e], s1 = csr[e + 1], s2 = csr[e + 2], s3 = csr[e + 3];
        float x0 = x[s0 * 5 + k_];
        float x1 = x[s1 * 5 + k_];
        float x2 = x[s2 * 5 + k_];
        float x3 = x[s3 * 5 + k_];
        float v0 = el[s0 * 4 + h_];
        float v1 = el[s1 * 4 + h_];
        float v2 = el[s2 * 4 + h_];
        float v3 = el[s3 * 4 + h_];
        A1_ACC(x0, v0) A1_ACC(x1, v1) A1_ACC(x2, v2) A1_ACC(x3, v3)
    }
    for (; e < e1; e++) {
        int s0 = csr[e];
        float x0 = x[s0 * 5 + k_];
        float v0 = el[s0 * 4 + h_];
        A1_ACC(x0, v0)
    }
#undef A1_ACC
    // epilogue: for each of the 3 dsts, broadcast acc[h][:] and project through W
#pragma unroll
    for (int g3 = 0; g3 < 3; g3++) {
        int dsto = dbase + g3;
        if (dsto >= Nn) break;  // wave-uniform
        float a_k[5];
#pragma unroll
        for (int k = 0; k < 5; k++) a_k[k] = __shfl(acc, g3 * 20 + myhead * 5 + k, 64);
        float s = __shfl(sh, g3 * 20 + myhead * 5, 64);
        float inv = 1.f / fmaxf(s, 1e-9f);
        float o0 = 0.f, o1 = 0.f, o2 = 0.f, o3 = 0.f;
#pragma unroll
        for (int k = 0; k < 5; k++) {
            o0 += a_k[k] * w0[k]; o1 += a_k[k] * w1[k];
            o2 += a_k[k] * w2[k]; o3 += a_k[k] * w3[k];
        }
        float4 o;
        o.x = leaky(o0 * inv, 0.01f);
        o.y = leaky(o1 * inv, 0.01f);
        o.z = leaky(o2 * inv, 0.01f);
        o.w = leaky(o3 * inv, 0.01f);
        *(float4*)(out + (size_t)dsto * 256 + c0) = o;
    }
}

// ---------------- gather aggregation: 2 dst/wave, 8 cols/lane (bf16 in, fp32 out) ----------------
template <int H, int LOGD, int HD>
__global__ __launch_bounds__(256, 4) void aggr4_kernel(const ushort* __restrict__ h,
                                                       const float* __restrict__ el,
                                                       const float* __restrict__ er,
                                                       const int* __restrict__ off,
                                                       const int* __restrict__ csr,
                                                       float* __restrict__ out, int Nn,
                                                       float oslope) {
    int wid = threadIdx.x >> 6;
    int lane = threadIdx.x & 63;
    int half = lane >> 5, hl = lane & 31;
    constexpr int NL = HD / 8;
    int d = blockIdx.x * 8 + wid * 2 + half;
    bool valid = (hl < NL) && (d < Nn);
    int dd = valid ? d : 0;
    int myhead = (hl * 8) >> LOGD;
    float erd = valid ? er[dd * H + myhead] : 0.f;
    float a0 = 0.f, a1 = 0.f, a2 = 0.f, a3 = 0.f;
    float a4 = 0.f, a5 = 0.f, a6 = 0.f, a7 = 0.f, s = 0.f;
    int e = valid ? off[dd] : 0;
    int e1 = valid ? off[dd + 1] : 0;
#define A8_ACC(EV, HR)                                      \
    {                                                       \
        float ev_ = (EV) + erd;                             \
        ev_ = ev_ >= 0.f ? ev_ : 0.2f * ev_;                \
        float w_ = __expf(fminf(ev_, 80.f));                \
        a0 += w_ * b2f((ushort)(HR).x);                     \
        a1 += w_ * b2f((ushort)((HR).x >> 16));             \
        a2 += w_ * b2f((ushort)(HR).y);                     \
        a3 += w_ * b2f((ushort)((HR).y >> 16));             \
        a4 += w_ * b2f((ushort)(HR).z);                     \
        a5 += w_ * b2f((ushort)((HR).z >> 16));             \
        a6 += w_ * b2f((ushort)(HR).w);                     \
        a7 += w_ * b2f((ushort)((HR).w >> 16));             \
        s += w_;                                            \
    }
#define A8_ACCM(OK, EV, HR)                                 \
    {                                                       \
        float ev_ = (EV) + erd;                             \
        ev_ = ev_ >= 0.f ? ev_ : 0.2f * ev_;                \
        float w_ = (OK) ? __expf(fminf(ev_, 80.f)) : 0.f;   \
        a0 += w_ * b2f((ushort)(HR).x);                     \
        a1 += w_ * b2f((ushort)((HR).x >> 16));             \
        a2 += w_ * b2f((ushort)(HR).y);                     \
        a3 += w_ * b2f((ushort)((HR).y >> 16));             \
        a4 += w_ * b2f((ushort)(HR).z);                     \
        a5 += w_ * b2f((ushort)((HR).z >> 16));             \
        a6 += w_ * b2f((ushort)(HR).w);                     \
        a7 += w_ * b2f((ushort)((HR).w >> 16));             \
        s += w_;                                            \
    }
    for (; e + 4 <= e1; e += 4) {
        int s0 = csr[e], s1 = csr[e + 1], s2 = csr[e + 2], s3 = csr[e + 3];
        float e0 = el[s0 * H + myhead];
        float e1v = el[s1 * H + myhead];
        float e2v = el[s2 * H + myhead];
        float e3v = el[s3 * H + myhead];
        uint4 h0 = *(const uint4*)(h + (size_t)s0 * HD + hl * 8);
        uint4 h1 = *(const uint4*)(h + (size_t)s1 * HD + hl * 8);
        uint4 h2 = *(const uint4*)(h + (size_t)s2 * HD + hl * 8);
        uint4 h3 = *(const uint4*)(h + (size_t)s3 * HD + hl * 8);
        A8_ACC(e0, h0) A8_ACC(e1v, h1) A8_ACC(e2v, h2) A8_ACC(e3v, h3)
    }
    if (e < e1) {
        bool k1 = e + 1 < e1, k2 = e + 2 < e1, k3 = e + 3 < e1;
        int s0 = csr[e];
        int s1 = csr[k1 ? e + 1 : e];
        int s2 = csr[k2 ? e + 2 : e];
        int s3 = csr[k3 ? e + 3 : e];
        float e0 = el[s0 * H + myhead];
        float e1v = el[s1 * H + myhead];
        float e2v = el[s2 * H + myhead];
        float e3v = el[s3 * H + myhead];
        uint4 h0 = *(const uint4*)(h + (size_t)s0 * HD + hl * 8);
        uint4 h1 = *(const uint4*)(h + (size_t)s1 * HD + hl * 8);
        uint4 h2 = *(const uint4*)(h + (size_t)s2 * HD + hl * 8);
        uint4 h3 = *(const uint4*)(h + (size_t)s3 * HD + hl * 8);
        A8_ACCM(true, e0, h0) A8_ACCM(k1, e1v, h1) A8_ACCM(k2, e2v, h2) A8_ACCM(k3, e3v, h3)
    }
#undef A8_ACC
#undef A8_ACCM
    if (valid) {
        float inv = 1.f / fmaxf(s, 1e-9f);
        float4 oa, ob;
        oa.x = leaky(a0 * inv, oslope);
        oa.y = leaky(a1 * inv, oslope);
        oa.z = leaky(a2 * inv, oslope);
        oa.w = leaky(a3 * inv, oslope);
        ob.x = leaky(a4 * inv, oslope);
        ob.y = leaky(a5 * inv, oslope);
        ob.z = leaky(a6 * inv, oslope);
        ob.w = leaky(a7 * inv, oslope);
        float* po = out + (size_t)dd * HD + hl * 8;
        *(float4*)(po) = oa;
        *(float4*)(po + 4) = ob;
    }
}

// final GAT layer: H=2, D=32, HD=64 — 2 dst/wave + block LDS pre-reduction before atomics
__global__ __launch_bounds__(256, 4) void aggr_mean_kernel(const ushort* __restrict__ h,
                                                           const float* __restrict__ el,
                                                           const float* __restrict__ er,
                                                           const int* __restrict__ off,
                                                           const int* __restrict__ csr,
                                                           const int* __restrict__ gid,
                                                           float* __restrict__ out_sum,
                                                           float* __restrict__ out_cnt,
                                                           int Nn) {
    __shared__ float red[8][32];
    __shared__ int gids[8];
    int wid = threadIdx.x >> 6;
    int lane = threadIdx.x & 63;
    int half = lane >> 5;
    int hl = lane & 31;
    int row = wid * 2 + half;
    int d = blockIdx.x * 8 + row;
    bool valid = d < Nn;
    int dd = valid ? d : 0;
    int head = hl >> 4;  // cols 2hl, 2hl+1; head1 when hl>=16
    float erd = er[dd * 2 + head];
    float a0 = 0.f, a1 = 0.f, s = 0.f;
    int e = valid ? off[dd] : 0;
    int e1 = valid ? off[dd + 1] : 0;
#define AM_ACC(Q, V)                                        \
    {                                                       \
        float ev_ = (head ? (Q).y : (Q).x) + erd;           \
        ev_ = ev_ >= 0.f ? ev_ : 0.2f * ev_;                \
        float w_ = __expf(fminf(ev_, 80.f));                \
        a0 += w_ * b2f((ushort)(V));                        \
        a1 += w_ * b2f((ushort)((V) >> 16));                \
        s += w_;                                            \
    }
#define AM_ACCM(OK, Q, V)                                   \
    {                                                       \
        float ev_ = (head ? (Q).y : (Q).x) + erd;           \
        ev_ = ev_ >= 0.f ? ev_ : 0.2f * ev_;                \
        float w_ = (OK) ? __expf(fminf(ev_, 80.f)) : 0.f;   \
        a0 += w_ * b2f((ushort)(V));                        \
        a1 += w_ * b2f((ushort)((V) >> 16));                \
        s += w_;                                            \
    }
    for (; e + 8 <= e1; e += 8) {
        int s0 = csr[e], s1 = csr[e + 1], s2 = csr[e + 2], s3 = csr[e + 3];
        int s4 = csr[e + 4], s5 = csr[e + 5], s6 = csr[e + 6], s7 = csr[e + 7];
        float2 q0 = *(const float2*)(el + s0 * 2);
        float2 q1 = *(const float2*)(el + s1 * 2);
        float2 q2 = *(const float2*)(el + s2 * 2);
        float2 q3 = *(const float2*)(el + s3 * 2);
        float2 q4 = *(const float2*)(el + s4 * 2);
        float2 q5 = *(const float2*)(el + s5 * 2);
        float2 q6 = *(const float2*)(el + s6 * 2);
        float2 q7 = *(const float2*)(el + s7 * 2);
        uint v0 = *(const uint*)(h + (size_t)s0 * 64 + hl * 2);
        uint v1 = *(const uint*)(h + (size_t)s1 * 64 + hl * 2);
        uint v2 = *(const uint*)(h + (size_t)s2 * 64 + hl * 2);
        uint v3 = *(const uint*)(h + (size_t)s3 * 64 + hl * 2);
        uint v4 = *(const uint*)(h + (size_t)s4 * 64 + hl * 2);
        uint v5 = *(const uint*)(h + (size_t)s5 * 64 + hl * 2);
        uint v6 = *(const uint*)(h + (size_t)s6 * 64 + hl * 2);
        uint v7 = *(const uint*)(h + (size_t)s7 * 64 + hl * 2);
        AM_ACC(q0, v0) AM_ACC(q1, v1) AM_ACC(q2, v2) AM_ACC(q3, v3)
        AM_ACC(q4, v4) AM_ACC(q5, v5) AM_ACC(q6, v6) AM_ACC(q7, v7)
    }
    if (e < e1) {
        bool k1 = e + 1 < e1, k2 = e + 2 < e1, k3 = e + 3 < e1;
        bool k4 = e + 4 < e1, k5 = e + 5 < e1, k6 = e + 6 < e1, k7 = e + 7 < e1;
        int s0 = csr[e];
        int s1 = csr[k1 ? e + 1 : e];
        int s2 = csr[k2 ? e + 2 : e];
        int s3 = csr[k3 ? e + 3 : e];
        int s4 = csr[k4 ? e + 4 : e];
        int s5 = csr[k5 ? e + 5 : e];
        int s6 = csr[k6 ? e + 6 : e];
        int s7 = csr[k7 ? e + 7 : e];
        float2 q0 = *(const float2*)(el + s0 * 2);
        float2 q1 = *(const float2*)(el + s1 * 2);
        float2 q2 = *(const float2*)(el + s2 * 2);
        float2 q3 = *(const float2*)(el + s3 * 2);
        float2 q4 = *(const float2*)(el + s4 * 2);
        float2 q5 = *(const float2*)(el + s5 * 2);
        float2 q6 = *(const float2*)(el + s6 * 2);
        float2 q7 = *(const float2*)(el + s7 * 2);
        uint v0 = *(const uint*)(h + (size_t)s0 * 64 + hl * 2);
        uint v1 = *(const uint*)(h + (size_t)s1 * 64 + hl * 2);
        uint v2 = *(const uint*)(h + (size_t)s2 * 64 + hl * 2);
        uint v3 = *(const uint*)(h + (size_t)s3 * 64 + hl * 2);
        uint v4 = *(const uint*)(h + (size_t)s4 * 64 + hl * 2);
        uint v5 = *(const uint*)(h + (size_t)s5 * 64 + hl * 2);
        uint v6 = *(const uint*)(h + (size_t)s6 * 64 + hl * 2);
        uint v7 = *(const uint*)(h + (size_t)s7 * 64 + hl * 2);
        AM_ACCM(true, q0, v0) AM_ACCM(k1, q1, v1) AM_ACCM(k2, q2, v2) AM_ACCM(k3, q3, v3)
        AM_ACCM(k4, q4, v4) AM_ACCM(k5, q5, v5) AM_ACCM(k6, q6, v6) AM_ACCM(k7, q7, v7)
    }
#undef AM_ACC
#undef AM_ACCM
    float inv = 1.f / fmaxf(s, 1e-9f);
    float y0 = a0 * inv, y1 = a1 * inv;
    // head-mean: col c pairs with c+32 -> lane hl+16 within same half
    float p0 = __shfl(y0, lane + 16, 64);
    float p1 = __shfl(y1, lane + 16, 64);
    if (hl < 16) {
        red[row][2 * hl] = valid ? 0.5f * (y0 + p0) : 0.f;
        red[row][2 * hl + 1] = valid ? 0.5f * (y1 + p1) : 0.f;
        if (hl == 0) gids[row] = valid ? (gid ? gid[d] : 0) : -1;
    }
    __syncthreads();
    // block-level reduction over runs of equal gid -> few device atomics
    if (threadIdx.x < 32) {
        int c = threadIdx.x;
        float sum = 0.f;
        int cur = gids[0];
#pragma unroll
        for (int r = 0; r < 8; r++) {
            int gr = gids[r];
            if (gr != cur) {
                if (cur >= 0) atomicAdd(&out_sum[cur * 32 + c], sum);
                sum = 0.f;
                cur = gr;
            }
            if (gr >= 0) sum += red[r][c];
        }
        if (cur >= 0) atomicAdd(&out_sum[cur * 32 + c], sum);
    } else if (threadIdx.x == 32 && out_cnt) {
        float cnt = 0.f;
        int cur = gids[0];
#pragma unroll
        for (int r = 0; r < 8; r++) {
            int gr = gids[r];
            if (gr != cur) {
                if (cur >= 0) atomicAdd(&out_cnt[cur], cnt);
                cnt = 0.f;
                cur = gr;
            }
            if (gr >= 0) cnt += 1.f;
        }
        if (cur >= 0) atomicAdd(&out_cnt[cur], cnt);
    }
}

// ---------------- GraphNorm column stats (fp32 input, 8-row unroll, scalarized) ----------------
__global__ void colstats_kernel(const float* __restrict__ x,
                                float* __restrict__ sum,
                                float* __restrict__ sumsq, int Nn) {
    int C = blockDim.x, c = threadIdx.x;
    int nb = gridDim.x;
    int chunk = (Nn + nb - 1) / nb;
    int r0 = blockIdx.x * chunk;
    int r1 = min(r0 + chunk, Nn);
    float ls = 0.f, lq = 0.f;
    int r = r0;
    for (; r + 8 <= r1; r += 8) {
        const float* p = x + (size_t)r * C + c;
        float v0 = p[0];
        float v1 = p[C];
        float v2 = p[2 * C];
        float v3 = p[3 * C];
        float v4 = p[4 * C];
        float v5 = p[5 * C];
        float v6 = p[6 * C];
        float v7 = p[7 * C];
        ls += ((v0 + v1) + (v2 + v3)) + ((v4 + v5) + (v6 + v7));
        lq += ((v0 * v0 + v1 * v1) + (v2 * v2 + v3 * v3)) +
              ((v4 * v4 + v5 * v5) + (v6 * v6 + v7 * v7));
    }
    for (; r < r1; r++) {
        float v = x[(size_t)r * C + c];
        ls += v; lq += v * v;
    }
    atomicAdd(&sum[c], ls);
    atomicAdd(&sumsq[c], lq);
}

// GraphNorm apply for readout: writes d_out (per flag) + fp32 mesh input
__global__ void gnorm_apply_ro_kernel(const float* __restrict__ x,
                                      const float* __restrict__ sum,
                                      const float* __restrict__ sumsq,
                                      const float* __restrict__ g,
                                      const float* __restrict__ b,
                                      const float* __restrict__ a,
                                      void* __restrict__ doutv,
                                      const int* __restrict__ flag,
                                      float* __restrict__ rof, int Nn) {
    int c = threadIdx.x;  // C = 32
    float invn = 1.f / (float)Nn;
    float mu = sum[c] * invn, ex2 = sumsq[c] * invn;
    float av = a[c];
    float var = ex2 - 2.f * av * mu * mu + av * av * mu * mu;
    float sc = g[c] * rsqrtf(var + 1e-5f);
    float sh = b[c] - sc * av * mu;
    bool fp32 = (*flag != 0);
    for (int r = blockIdx.x; r < Nn; r += gridDim.x) {
        int i = r * 32 + c;
        float v = x[i] * sc + sh;
        rof[i] = v;
        if (fp32) ((float*)doutv)[15 + i] = v;
        else      ((ushort*)doutv)[15 + i] = f2b(v);
    }
}

// ---------------- readout: segment-mean @ pcls + leaky (fp32 out) ----------------
__global__ __launch_bounds__(256) void readout_kernel(const float* __restrict__ ro_sum,
                                                      const float* __restrict__ ro_cnt,
                                                      const float* __restrict__ pcls,
                                                      float* __restrict__ ro_lin, int NGc) {
    int idx = blockIdx.x * blockDim.x + threadIdx.x;
    int g = idx >> 5, c = idx & 31;
    if (g >= NGc) return;
    float inv = 1.f / fmaxf(ro_cnt[g], 1.f);
    float acc = 0.f;
#pragma unroll
    for (int k = 0; k < 32; k++) acc += ro_sum[g * 32 + k] * inv * pcls[k * 32 + c];
    ro_lin[g * 32 + c] = leaky(acc, 0.01f);
}

// ---------------- MFMA GEMM: C(bf16) = gnorm(A:fp32) @ B, fused gnfin + elr ----------------
template <int K, int N, int H, int LOGD, bool GN>
__global__ __launch_bounds__(256) void gemm_kernel(const float* __restrict__ A,
                                                   const float* __restrict__ B,
                                                   const float* __restrict__ csum,
                                                   const float* __restrict__ g,
                                                   const float* __restrict__ gb,
                                                   const float* __restrict__ ga,
                                                   const float* __restrict__ al,
                                                   const float* __restrict__ ar,
                                                   ushort* __restrict__ C,
                                                   float* __restrict__ el,
                                                   float* __restrict__ er, int M) {
    constexpr int NT = N / 16;
    constexpr int AROW = 40;
    __shared__ __align__(16) ushort Alds[64 * AROW];
    __shared__ __align__(16) ushort Blds[32 * N];  // swizzled [k/8][n][k%8]
    __shared__ float ScL[256], ShL[256];
    int tid = threadIdx.x;
    int w = tid >> 6, lane = tid & 63, q = lane >> 4, l16 = lane & 15;
    int m0 = blockIdx.x * 64;
    if (GN && tid < K) {
        float invn = 1.f / (float)M;
        float mu = csum[tid] * invn, ex2 = csum[512 + tid] * invn;
        float av = ga[tid];
        float var = ex2 - 2.f * av * mu * mu + av * av * mu * mu;
        float sc = g[tid] * rsqrtf(var + 1e-5f);
        ScL[tid] = sc;
        ShL[tid] = gb[tid] - sc * av * mu;
    }
    float4v acc[NT];
#pragma unroll
    for (int nt = 0; nt < NT; nt++) acc[nt] = (float4v){0.f, 0.f, 0.f, 0.f};

    for (int kc = 0; kc < K; kc += 32) {
        __syncthreads();
        {
#pragma unroll
            for (int it = 0; it < 2; it++) {
                int idx = it * 256 + tid;
                int r = idx >> 3;
                int c4 = (idx & 7) * 4;
                int gr = m0 + r;
                float4 av = {0.f, 0.f, 0.f, 0.f};
                if (gr < M) av = *(const float4*)(A + (size_t)gr * K + kc + c4);
                if (GN) {
                    av.x = av.x * ScL[kc + c4] + ShL[kc + c4];
                    av.y = av.y * ScL[kc + c4 + 1] + ShL[kc + c4 + 1];
                    av.z = av.z * ScL[kc + c4 + 2] + ShL[kc + c4 + 2];
                    av.w = av.w * ScL[kc + c4 + 3] + ShL[kc + c4 + 3];
                }
                uint2 pk;
                pk.x = (uint)f2b(av.x) | ((uint)f2b(av.y) << 16);
                pk.y = (uint)f2b(av.z) | ((uint)f2b(av.w) << 16);
                *(uint2*)(&Alds[r * AROW + c4]) = pk;
            }
        }
        {
            constexpr int PAIRS = 16 * N;
#pragma unroll
            for (int p0 = 0; p0 < PAIRS; p0 += 256) {
                int p = p0 + tid;
                int k_ = p / (N / 2);
                int n0 = (p % (N / 2)) * 2;
                float2 bv = *(const float2*)(B + (size_t)(kc + k_) * N + n0);
                int base = (((k_ >> 3) * N + n0) << 3) + (k_ & 7);
                Blds[base] = f2b(bv.x);
                Blds[base + 8] = f2b(bv.y);
            }
        }
        __syncthreads();
        short8 a = *(const short8*)(&Alds[(w * 16 + l16) * AROW + q * 8]);
#pragma unroll
        for (int nt = 0; nt < NT; nt++) {
            short8 b = *(const short8*)(&Blds[(q * N + nt * 16 + l16) * 8]);
            acc[nt] = __builtin_amdgcn_mfma_f32_16x16x32_bf16(a, b, acc[nt], 0, 0, 0);
        }
    }
    // store C (bf16) + fused el/er
    float pel[4][H], per[4][H];
#pragma unroll
    for (int i = 0; i < 4; i++)
#pragma unroll
        for (int hh = 0; hh < H; hh++) { pel[i][hh] = 0.f; per[i][hh] = 0.f; }
#pragma unroll
    for (int nt = 0; nt < NT; nt++) {
        int col = nt * 16 + l16;
        float alc = al[col], arc = ar[col];
        constexpr int HSH = LOGD - 4;
        int hh = nt >> HSH;
#pragma unroll
        for (int i = 0; i < 4; i++) {
            int row = m0 + w * 16 + q * 4 + i;
            float v = acc[nt][i];
            if (row < M) C[(size_t)row * N + col] = f2b(v);
            pel[i][hh] += v * alc;
            per[i][hh] += v * arc;
        }
    }
#pragma unroll
    for (int i = 0; i < 4; i++) {
#pragma unroll
        for (int hh = 0; hh < H; hh++) {
            float vl = pel[i][hh], vr = per[i][hh];
#pragma unroll
            for (int m = 1; m < 16; m <<= 1) {
                vl += __shfl_xor(vl, m, 64);
                vr += __shfl_xor(vr, m, 64);
            }
            if (l16 == 0) {
                int row = m0 + w * 16 + q * 4 + i;
                if (row < M) { el[row * H + hh] = vl; er[row * H + hh] = vr; }
            }
        }
    }
}

// ---------------- final: node-mean @ mcls ----------------
__global__ __launch_bounds__(64) void final_kernel(const float* __restrict__ msum,
                                                   const float* __restrict__ mcls,
                                                   void* __restrict__ doutv,
                                                   const int* __restrict__ flag, int Nm) {
    int t = threadIdx.x;
    if (t < 15) {
        float inv = 1.f / (float)Nm;
        float acc = 0.f;
#pragma unroll
        for (int c = 0; c < 32; c++) acc += msum[c] * inv * mcls[c * 15 + t];
        if (*flag) ((float*)doutv)[t] = acc;
        else       ((ushort*)doutv)[t] = f2b(acc);
    }
}

extern "C" void kernel_launch(void* const* d_in, const int* in_sizes, int n_in,
                              void* d_out, int out_size, void* d_ws, size_t ws_size,
                              hipStream_t stream) {
    const int NP = 100000, NG = 2000, EP = 800000, NM = 2000, EM = 32000;

    const int* patch_src = (const int*)d_in[1];
    const int* patch_dst = (const int*)d_in[2];
    const int* patch_gid = (const int*)d_in[3];
    const int* mesh_src = (const int*)d_in[4];
    const int* mesh_dst = (const int*)d_in[5];

    char* p = (char*)d_ws;
    auto alloc = [&](size_t bytes) -> char* {
        char* r = p;
        p += (bytes + 255) & ~(size_t)255;
        return r;
    };
    char* zbase = p;
    int* cnt_p = (int*)alloc((size_t)NP * 4);
    int* cursor_p = (int*)alloc((size_t)NP * 4);
    int* cnt_m = (int*)alloc((size_t)NM * 4);
    int* cursor_m = (int*)alloc((size_t)NM * 4);
    float* ro_sum = (float*)alloc((size_t)NG * 32 * 4);
    float* ro_cnt = (float*)alloc((size_t)NG * 4);
    float* msum = (float*)alloc(32 * 4);
    float* colbuf = (float*)alloc(6 * 1024 * 4);
    size_t zbytes = (size_t)(p - zbase);
    int* flag = (int*)alloc(256);
    int* off_p = (int*)alloc((size_t)(NP + 1) * 4);
    int* off_m = (int*)alloc((size_t)(NM + 1) * 4);
    int* bsum_p = (int*)alloc(64 * 4);
    int* bsum_m = (int*)alloc(16 * 4);
    int* csr_p = (int*)alloc((size_t)EP * 4);
    int* csr_m = (int*)alloc((size_t)EM * 4);
    float* el = (float*)alloc((size_t)NP * 4 * 4);
    float* er = (float*)alloc((size_t)NP * 4 * 4);
    ushort* hbuf = (ushort*)alloc((size_t)NP * 256 * 2);   // bf16 gather buffer
    float* gbuf = (float*)alloc((size_t)NP * 256 * 4);     // fp32 aggr output
    ushort* hm = (ushort*)alloc((size_t)NM * 256 * 2);
    float* gm = (float*)alloc((size_t)NM * 256 * 4);
    float* elm = (float*)alloc((size_t)NM * 4 * 4);
    float* erm = (float*)alloc((size_t)NM * 4 * 4);
    float* ro_lin = (float*)alloc((size_t)NG * 32 * 4);
    float* ro_f = (float*)alloc((size_t)NG * 32 * 4);

    ConvArgs ca;
    float* convp[36];
    int conv_idx[36];
    conv_idx[0] = 0;
    for (int i = 1; i < 36; i++) conv_idx[i] = 5 + i;
    for (int j = 0; j < 36; j++) {
        int ii = conv_idx[j];
        int n = in_sizes[ii];
        float* dd = (float*)alloc((size_t)n * 4);
        ca.s[j] = d_in[ii];
        ca.d[j] = dd;
        ca.n[j] = n;
        convp[j] = dd;
    }
    ca.s[36] = nullptr;
    ca.d[36] = (float*)zbase;
    ca.n[36] = (int)(zbytes / 4);

    const float* xf = convp[0];
    const float *pW1f = convp[1], *pal1f = convp[2], *par1f = convp[3];
    const float *pg1_gf = convp[4], *pg1_bf = convp[5], *pg1_af = convp[6];
    const float *pW2f = convp[7], *pal2f = convp[8], *par2f = convp[9];
    const float *pg2_gf = convp[10], *pg2_bf = convp[11], *pg2_af = convp[12];
    const float *pW3f = convp[13], *pal3f = convp[14], *par3f = convp[15];
    const float* pclsf = convp[16];
    const float *rn_gf = convp[17], *rn_bf2 = convp[18], *rn_af = convp[19];
    const float *mW1f = convp[20], *mal1f = convp[21], *mar1f = convp[22];
    const float *mg1_gf = convp[23], *mg1_bf = convp[24], *mg1_af = convp[25];
    const float *mW2f = convp[26], *mal2f = convp[27], *mar2f = convp[28];
    const float *mg2_gf = convp[29], *mg2_bf = convp[30], *mg2_af = convp[31];
    const float *mW3f = convp[32], *mal3f = convp[33], *mar3f = convp[34];
    const float* mclsf = convp[35];

    convert_kernel<<<dim3(16, 37), 256, 0, stream>>>(ca, (const ushort*)d_in[0], flag);

    const int SBP = (NP + 2047) / 2048, SBM = (NM + 2047) / 2048;
    hist_both<<<512 + 64, 256, 0, stream>>>(patch_dst, cnt_p, EP, mesh_dst, cnt_m, EM, 512);
    scan_both<<<SBP + SBM, 256, 0, stream>>>(cnt_p, off_p, bsum_p, NP, SBP, cnt_m, off_m, bsum_m, NM);
    fixup_both<<<SBP + SBM, 256, 0, stream>>>(bsum_p, off_p, NP, SBP, bsum_m, off_m, NM, SBM);
    scatter_both<<<512 + 64, 256, 0, stream>>>(patch_src, patch_dst, off_p, cursor_p, csr_p, EP,
                                               mesh_src, mesh_dst, off_m, cursor_m, csr_m, EM, 512);

    int gP = (NP + 3) / 4;
    int gP12 = (NP + 11) / 12;
    int gA2 = (NP + 7) / 8, gA2m = (NM + 7) / 8;
    int gP2 = (NP + 7) / 8, gM2 = (NM + 7) / 8;
    int gT = (NP + 63) / 64, gTm = (NM + 63) / 64;
    float* cb0 = colbuf + 0 * 1024;
    float* cb1 = colbuf + 1 * 1024;
    float* cb2 = colbuf + 2 * 1024;
    float* cb3 = colbuf + 3 * 1024;
    float* cb4 = colbuf + 4 * 1024;

    // ---- patch GAT layer 1 ----
    proj1_elr_kernel<<<gP, 256, 0, stream>>>(xf, pW1f, pal1f, par1f, el, er, NP);
    aggr1_fly_kernel<<<gP12, 256, 0, stream>>>(xf, pW1f, el, er, off_p, csr_p, gbuf, NP);
    colstats_kernel<<<512, 256, 0, stream>>>(gbuf, cb0, cb0 + 512, NP);

    // ---- patch GAT layer 2 ----
    gemm_kernel<256, 192, 3, 6, true><<<gT, 256, 0, stream>>>(
        gbuf, pW2f, cb0, pg1_gf, pg1_bf, pg1_af, pal2f, par2f, hbuf, el, er, NP);
    aggr4_kernel<3, 6, 192><<<gA2, 256, 0, stream>>>(hbuf, el, er, off_p, csr_p, gbuf, NP, 0.01f);
    colstats_kernel<<<512, 192, 0, stream>>>(gbuf, cb1, cb1 + 512, NP);

    // ---- patch GAT layer 3 + readout ----
    gemm_kernel<192, 64, 2, 5, true><<<gT, 256, 0, stream>>>(
        gbuf, pW3f, cb1, pg2_gf, pg2_bf, pg2_af, pal3f, par3f, hbuf, el, er, NP);
    aggr_mean_kernel<<<gP2, 256, 0, stream>>>(hbuf, el, er, off_p, csr_p, patch_gid,
                                              ro_sum, ro_cnt, NP);

    readout_kernel<<<(NG * 32 + 255) / 256, 256, 0, stream>>>(ro_sum, ro_cnt, pclsf, ro_lin, NG);
    colstats_kernel<<<64, 32, 0, stream>>>(ro_lin, cb2, cb2 + 512, NG);
    gnorm_apply_ro_kernel<<<64, 32, 0, stream>>>(ro_lin, cb2, cb2 + 512, rn_gf, rn_bf2, rn_af,
                                                 d_out, flag, ro_f, NG);

    // ---- mesh GAT layer 1 ----
    gemm_kernel<32, 256, 4, 6, false><<<gTm, 256, 0, stream>>>(
        ro_f, mW1f, nullptr, nullptr, nullptr, nullptr, mal1f, mar1f, hm, elm, erm, NM);
    aggr4_kernel<4, 6, 256><<<gA2m, 256, 0, stream>>>(hm, elm, erm, off_m, csr_m, gm, NM, 0.01f);
    colstats_kernel<<<64, 256, 0, stream>>>(gm, cb3, cb3 + 512, NM);

    // ---- mesh GAT layer 2 ----
    gemm_kernel<256, 96, 3, 5, true><<<gTm, 256, 0, stream>>>(
        gm, mW2f, cb3, mg1_gf, mg1_bf, mg1_af, mal2f, mar2f, hm, elm, erm, NM);
    aggr4_kernel<3, 5, 96><<<gA2m, 256, 0, stream>>>(hm, elm, erm, off_m, csr_m, gm, NM, 0.01f);
    colstats_kernel<<<64, 96, 0, stream>>>(gm, cb4, cb4 + 512, NM);

    // ---- mesh GAT layer 3 ----
    gemm_kernel<96, 64, 2, 5, true><<<gTm, 256, 0, stream>>>(
        gm, mW3f, cb4, mg2_gf, mg2_bf, mg2_af, mal3f, mar3f, hm, elm, erm, NM);
    aggr_mean_kernel<<<gM2, 256, 0, stream>>>(hm, elm, erm, off_m, csr_m, nullptr,
                                              msum, nullptr, NM);
    final_kernel<<<1, 64, 0, stream>>>(msum, mclsf, d_out, flag, NM);

    (void)n_in; (void)out_size; (void)ws_size;
}

// Round 17
// 674.586 us; speedup vs baseline: 1.3024x; 1.0425x over previous
//
#include <hip/hip_runtime.h>

typedef unsigned short ushort;
typedef unsigned int uint;
typedef __attribute__((ext_vector_type(8))) short short8;
typedef __attribute__((ext_vector_type(4))) float float4v;

#define DEV __device__ __forceinline__

DEV float b2f(ushort u) {
    union { uint i; float f; } v; v.i = ((uint)u) << 16; return v.f;
}
DEV ushort f2b(float f) {
    union { float f; uint i; } v; v.f = f;
    uint x = v.i;
    uint r = x + 0x7fffu + ((x >> 16) & 1u);
    return (ushort)(r >> 16);
}
DEV float leaky(float x, float s) { return x >= 0.f ? x : s * x; }

// ---------------- convert (+local sniff, +zero slice, +flag write) ----------------
struct ConvArgs {
    const void* s[37];
    float* d[37];
    int n[37];
};

__global__ __launch_bounds__(256) void convert_kernel(ConvArgs a, const ushort* __restrict__ x0,
                                                      int* __restrict__ flag) {
    __shared__ int sfp32;
    int tid = threadIdx.x;
    if (tid < 64) {
        int cnt = 0;
        for (int j = 0; j < 8; j++) {
            ushort u = x0[(tid * 8 + j) * 2];
            int e = (u >> 7) & 0xFF;
            if (e >= 100 && e <= 140) cnt++;
        }
#pragma unroll
        for (int m = 1; m < 64; m <<= 1) cnt += __shfl_xor(cnt, m, 64);
        if (tid == 0) sfp32 = (cnt < 256) ? 1 : 0;
    }
    __syncthreads();
    bool fp32 = (sfp32 != 0);
    if (blockIdx.x == 0 && blockIdx.y == 0 && tid == 0) *flag = fp32 ? 1 : 0;

    int ai = blockIdx.y;
    int n = a.n[ai];
    const void* s = a.s[ai];
    float* d = a.d[ai];
    int stride = gridDim.x * blockDim.x;
    if (s == nullptr) {
        for (int i = blockIdx.x * blockDim.x + tid; i < n; i += stride) d[i] = 0.f;
    } else {
        for (int i = blockIdx.x * blockDim.x + tid; i < n; i += stride)
            d[i] = fp32 ? ((const float*)s)[i] : b2f(((const ushort*)s)[i]);
    }
}

// ---------------- CSR build (patch+mesh merged) ----------------
__global__ __launch_bounds__(256) void hist_both(const int* __restrict__ dstP, int* __restrict__ cntP, int EPc,
                                                 const int* __restrict__ dstM, int* __restrict__ cntM, int EMc,
                                                 int PB) {
    bool patch = (int)blockIdx.x < PB;
    const int* dst = patch ? dstP : dstM;
    int* cnt = patch ? cntP : cntM;
    int E = patch ? EPc : EMc;
    int nb = patch ? PB : gridDim.x - PB;
    int b = patch ? blockIdx.x : blockIdx.x - PB;
    int stride = nb * blockDim.x;
    for (int i = b * blockDim.x + threadIdx.x; i < E; i += stride)
        atomicAdd(&cnt[dst[i]], 1);
}

__global__ __launch_bounds__(256) void scan_both(const int* __restrict__ cntP, int* __restrict__ offP,
                                                 int* __restrict__ bsumP, int nP, int SBP,
                                                 const int* __restrict__ cntM, int* __restrict__ offM,
                                                 int* __restrict__ bsumM, int nM) {
    __shared__ int ls[256];
    bool patch = (int)blockIdx.x < SBP;
    const int* cnt = patch ? cntP : cntM;
    int* off = patch ? offP : offM;
    int* bsum = patch ? bsumP : bsumM;
    int n = patch ? nP : nM;
    int b = patch ? blockIdx.x : blockIdx.x - SBP;
    int t = threadIdx.x;
    int base = b * 2048 + t * 8;
    int v[8];
    int s = 0;
#pragma unroll
    for (int i = 0; i < 8; i++) {
        int idx = base + i;
        v[i] = idx < n ? cnt[idx] : 0;
        s += v[i];
    }
    ls[t] = s;
    __syncthreads();
#pragma unroll
    for (int d = 1; d < 256; d <<= 1) {
        int add = (t >= d) ? ls[t - d] : 0;
        __syncthreads();
        ls[t] += add;
        __syncthreads();
    }
    int run = ls[t] - s;
#pragma unroll
    for (int i = 0; i < 8; i++) {
        int idx = base + i;
        if (idx < n) off[idx] = run;
        run += v[i];
    }
    if (t == 255) bsum[b] = ls[255];
}

__global__ __launch_bounds__(256) void fixup_both(const int* __restrict__ bsumP, int* __restrict__ offP,
                                                  int nP, int SBP,
                                                  const int* __restrict__ bsumM, int* __restrict__ offM,
                                                  int nM, int SBM) {
    bool patch = (int)blockIdx.x < SBP;
    const int* bsum = patch ? bsumP : bsumM;
    int* off = patch ? offP : offM;
    int n = patch ? nP : nM;
    int nb = patch ? SBP : SBM;
    int b = patch ? blockIdx.x : blockIdx.x - SBP;
    int t = threadIdx.x;
    int base = 0;
    for (int i = 0; i < b; i++) base += bsum[i];
    int idx0 = b * 2048 + t * 8;
    if (base != 0) {
#pragma unroll
        for (int i = 0; i < 8; i++) {
            int idx = idx0 + i;
            if (idx < n) off[idx] += base;
        }
    }
    if (b == nb - 1 && t == 255) off[n] = base + bsum[b];
}

__global__ __launch_bounds__(256) void scatter_both(const int* __restrict__ srcP, const int* __restrict__ dstP,
                                                    const int* __restrict__ offP, int* __restrict__ curP,
                                                    int* __restrict__ csrP, int EPc,
                                                    const int* __restrict__ srcM, const int* __restrict__ dstM,
                                                    const int* __restrict__ offM, int* __restrict__ curM,
                                                    int* __restrict__ csrM, int EMc, int PB) {
    bool patch = (int)blockIdx.x < PB;
    const int* src = patch ? srcP : srcM;
    const int* dst = patch ? dstP : dstM;
    const int* off = patch ? offP : offM;
    int* cursor = patch ? curP : curM;
    int* csr = patch ? csrP : csrM;
    int E = patch ? EPc : EMc;
    int nb = patch ? PB : gridDim.x - PB;
    int b = patch ? blockIdx.x : blockIdx.x - PB;
    int stride = nb * blockDim.x;
    for (int i = b * blockDim.x + threadIdx.x; i < E; i += stride) {
        int d = dst[i];
        int pos = off[d] + atomicAdd(&cursor[d], 1);
        csr[pos] = src[i];
    }
}

// ---------------- layer-1: el/er only ----------------
__global__ __launch_bounds__(256) void proj1_elr_kernel(const float* __restrict__ x,
                                                        const float* __restrict__ W,
                                                        const float* __restrict__ al,
                                                        const float* __restrict__ ar,
                                                        float* __restrict__ el,
                                                        float* __restrict__ er, int Nn) {
    int t = threadIdx.x;
    int head = t >> 6, lane = t & 63;
    float wv[5];
#pragma unroll
    for (int k = 0; k < 5; k++) wv[k] = W[k * 256 + t];
    float alv = al[t];
    float arv = ar[t];
    int n0 = blockIdx.x * 4;
    int n1 = min(n0 + 4, Nn);
    for (int n = n0; n < n1; n++) {
        float acc = 0.f;
#pragma unroll
        for (int k = 0; k < 5; k++) acc += x[n * 5 + k] * wv[k];
        float pl = acc * alv, pr = acc * arv;
#pragma unroll
        for (int m = 1; m < 64; m <<= 1) {
            pl += __shfl_xor(pl, m, 64);
            pr += __shfl_xor(pr, m, 64);
        }
        if (lane == 0) { el[n * 4 + head] = pl; er[n * 4 + head] = pr; }
    }
}

// ---------------- patch layer-1 aggregation: outer-product, 3 dst per wave ----------------
__global__ __launch_bounds__(256, 4) void aggr1_fly_kernel(const float* __restrict__ x,
                                                           const float* __restrict__ W,
                                                           const float* __restrict__ el,
                                                           const float* __restrict__ er,
                                                           const int* __restrict__ off,
                                                           const int* __restrict__ csr,
                                                           float* __restrict__ out, int Nn) {
    int wid = threadIdx.x >> 6;
    int lane = threadIdx.x & 63;
    int grp = lane / 20;          // 0..3 (grp 3 idle for edge work)
    int gl = lane - grp * 20;
    int dbase = blockIdx.x * 12 + wid * 3;
    int d = dbase + grp;
    bool accl = (grp < 3) && (d < Nn);
    int dd = accl ? d : 0;
    int h_ = gl / 5, k_ = gl - h_ * 5;  // h_ 0..3, k_ 0..4
    int c0 = lane * 4;
    int myhead = lane >> 4;
    float w0[5], w1[5], w2[5], w3[5];
#pragma unroll
    for (int k = 0; k < 5; k++) {
        float4 wv = *(const float4*)(W + k * 256 + c0);
        w0[k] = wv.x; w1[k] = wv.y; w2[k] = wv.z; w3[k] = wv.w;
    }
    float erd = accl ? er[dd * 4 + h_] : 0.f;
    float acc = 0.f, sh = 0.f;
    int e = accl ? off[dd] : 0;
    int e1 = accl ? off[dd + 1] : 0;
#define A1_ACC(XV, EV)                                  \
    {                                                   \
        float e0_ = (EV) + erd;                         \
        e0_ = e0_ >= 0.f ? e0_ : 0.2f * e0_;            \
        float w_ = __expf(fminf(e0_, 80.f));            \
        acc += w_ * (XV);                               \
        sh += w_;                                       \
    }
    for (; e + 4 <= e1; e += 4) {
        int s0 = csr[e], s1 = csr[e + 1], s2 = csr[e + 2], s3 = csr[e + 3];
        float x0 = x[s0 * 5 + k_];
        float x1 = x[s1 * 5 + k_];
        float x2 = x[s2 * 5 + k_];
        float x3 = x[s3 * 5 + k_];
        float v0 = el[s0 * 4 + h_];
        float v1 = el[s1 * 4 + h_];
        float v2 = el[s2 * 4 + h_];
        float v3 = el[s3 * 4 + h_];
        A1_ACC(x0, v0) A1_ACC(x1, v1) A1_ACC(x2, v2) A1_ACC(x3, v3)
    }
    for (; e < e1; e++) {
        int s0 = csr[e];
        float x0 = x[s0 * 5 + k_];
        float v0 = el[s0 * 4 + h_];
        A1_ACC(x0, v0)
    }
#undef A1_ACC
    // epilogue: for each of the 3 dsts, broadcast acc[h][:] and project through W
#pragma unroll
    for (int g3 = 0; g3 < 3; g3++) {
        int dsto = dbase + g3;
        if (dsto >= Nn) break;  // wave-uniform
        float a_k[5];
#pragma unroll
        for (int k = 0; k < 5; k++) a_k[k] = __shfl(acc, g3 * 20 + myhead * 5 + k, 64);
        float s = __shfl(sh, g3 * 20 + myhead * 5, 64);
        float inv = 1.f / fmaxf(s, 1e-9f);
        float o0 = 0.f, o1 = 0.f, o2 = 0.f, o3 = 0.f;
#pragma unroll
        for (int k = 0; k < 5; k++) {
            o0 += a_k[k] * w0[k]; o1 += a_k[k] * w1[k];
            o2 += a_k[k] * w2[k]; o3 += a_k[k] * w3[k];
        }
        float4 o;
        o.x = leaky(o0 * inv, 0.01f);
        o.y = leaky(o1 * inv, 0.01f);
        o.z = leaky(o2 * inv, 0.01f);
        o.w = leaky(o3 * inv, 0.01f);
        *(float4*)(out + (size_t)dsto * 256 + c0) = o;
    }
}

// ---------------- gather aggregation: 2 dst/wave, 8 cols/lane (bf16 in, fp32 out) ----------------
template <int H, int LOGD, int HD>
__global__ __launch_bounds__(256, 4) void aggr4_kernel(const ushort* __restrict__ h,
                                                       const float* __restrict__ el,
                                                       const float* __restrict__ er,
                                                       const int* __restrict__ off,
                                                       const int* __restrict__ csr,
                                                       float* __restrict__ out, int Nn,
                                                       float oslope) {
    int wid = threadIdx.x >> 6;
    int lane = threadIdx.x & 63;
    int half = lane >> 5, hl = lane & 31;
    constexpr int NL = HD / 8;
    int d = blockIdx.x * 8 + wid * 2 + half;
    bool valid = (hl < NL) && (d < Nn);
    int dd = valid ? d : 0;
    int myhead = (hl * 8) >> LOGD;
    float erd = valid ? er[dd * H + myhead] : 0.f;
    float a0 = 0.f, a1 = 0.f, a2 = 0.f, a3 = 0.f;
    float a4 = 0.f, a5 = 0.f, a6 = 0.f, a7 = 0.f, s = 0.f;
    int e = valid ? off[dd] : 0;
    int e1 = valid ? off[dd + 1] : 0;
#define A8_ACC(EV, HR)                                      \
    {                                                       \
        float ev_ = (EV) + erd;                             \
        ev_ = ev_ >= 0.f ? ev_ : 0.2f * ev_;                \
        float w_ = __expf(fminf(ev_, 80.f));                \
        a0 += w_ * b2f((ushort)(HR).x);                     \
        a1 += w_ * b2f((ushort)((HR).x >> 16));             \
        a2 += w_ * b2f((ushort)(HR).y);                     \
        a3 += w_ * b2f((ushort)((HR).y >> 16));             \
        a4 += w_ * b2f((ushort)(HR).z);                     \
        a5 += w_ * b2f((ushort)((HR).z >> 16));             \
        a6 += w_ * b2f((ushort)(HR).w);                     \
        a7 += w_ * b2f((ushort)((HR).w >> 16));             \
        s += w_;                                            \
    }
#define A8_ACCM(OK, EV, HR)                                 \
    {                                                       \
        float ev_ = (EV) + erd;                             \
        ev_ = ev_ >= 0.f ? ev_ : 0.2f * ev_;                \
        float w_ = (OK) ? __expf(fminf(ev_, 80.f)) : 0.f;   \
        a0 += w_ * b2f((ushort)(HR).x);                     \
        a1 += w_ * b2f((ushort)((HR).x >> 16));             \
        a2 += w_ * b2f((ushort)(HR).y);                     \
        a3 += w_ * b2f((ushort)((HR).y >> 16));             \
        a4 += w_ * b2f((ushort)(HR).z);                     \
        a5 += w_ * b2f((ushort)((HR).z >> 16));             \
        a6 += w_ * b2f((ushort)(HR).w);                     \
        a7 += w_ * b2f((ushort)((HR).w >> 16));             \
        s += w_;                                            \
    }
    for (; e + 4 <= e1; e += 4) {
        int s0 = csr[e], s1 = csr[e + 1], s2 = csr[e + 2], s3 = csr[e + 3];
        float e0 = el[s0 * H + myhead];
        float e1v = el[s1 * H + myhead];
        float e2v = el[s2 * H + myhead];
        float e3v = el[s3 * H + myhead];
        uint4 h0 = *(const uint4*)(h + (size_t)s0 * HD + hl * 8);
        uint4 h1 = *(const uint4*)(h + (size_t)s1 * HD + hl * 8);
        uint4 h2 = *(const uint4*)(h + (size_t)s2 * HD + hl * 8);
        uint4 h3 = *(const uint4*)(h + (size_t)s3 * HD + hl * 8);
        A8_ACC(e0, h0) A8_ACC(e1v, h1) A8_ACC(e2v, h2) A8_ACC(e3v, h3)
    }
    if (e < e1) {
        bool k1 = e + 1 < e1, k2 = e + 2 < e1, k3 = e + 3 < e1;
        int s0 = csr[e];
        int s1 = csr[k1 ? e + 1 : e];
        int s2 = csr[k2 ? e + 2 : e];
        int s3 = csr[k3 ? e + 3 : e];
        float e0 = el[s0 * H + myhead];
        float e1v = el[s1 * H + myhead];
        float e2v = el[s2 * H + myhead];
        float e3v = el[s3 * H + myhead];
        uint4 h0 = *(const uint4*)(h + (size_t)s0 * HD + hl * 8);
        uint4 h1 = *(const uint4*)(h + (size_t)s1 * HD + hl * 8);
        uint4 h2 = *(const uint4*)(h + (size_t)s2 * HD + hl * 8);
        uint4 h3 = *(const uint4*)(h + (size_t)s3 * HD + hl * 8);
        A8_ACCM(true, e0, h0) A8_ACCM(k1, e1v, h1) A8_ACCM(k2, e2v, h2) A8_ACCM(k3, e3v, h3)
    }
#undef A8_ACC
#undef A8_ACCM
    if (valid) {
        float inv = 1.f / fmaxf(s, 1e-9f);
        float4 oa, ob;
        oa.x = leaky(a0 * inv, oslope);
        oa.y = leaky(a1 * inv, oslope);
        oa.z = leaky(a2 * inv, oslope);
        oa.w = leaky(a3 * inv, oslope);
        ob.x = leaky(a4 * inv, oslope);
        ob.y = leaky(a5 * inv, oslope);
        ob.z = leaky(a6 * inv, oslope);
        ob.w = leaky(a7 * inv, oslope);
        float* po = out + (size_t)dd * HD + hl * 8;
        *(float4*)(po) = oa;
        *(float4*)(po + 4) = ob;
    }
}

// final GAT layer: H=2, D=32, HD=64 — 2 dst/wave + block LDS pre-reduction before atomics
__global__ __launch_bounds__(256, 4) void aggr_mean_kernel(const ushort* __restrict__ h,
                                                           const float* __restrict__ el,
                                                           const float* __restrict__ er,
                                                           const int* __restrict__ off,
                                                           const int* __restrict__ csr,
                                                           const int* __restrict__ gid,
                                                           float* __restrict__ out_sum,
                                                           float* __restrict__ out_cnt,
                                                           int Nn) {
    __shared__ float red[8][32];
    __shared__ int gids[8];
    int wid = threadIdx.x >> 6;
    int lane = threadIdx.x & 63;
    int half = lane >> 5;
    int hl = lane & 31;
    int row = wid * 2 + half;
    int d = blockIdx.x * 8 + row;
    bool valid = d < Nn;
    int dd = valid ? d : 0;
    int head = hl >> 4;  // cols 2hl, 2hl+1; head1 when hl>=16
    float erd = er[dd * 2 + head];
    float a0 = 0.f, a1 = 0.f, s = 0.f;
    int e = valid ? off[dd] : 0;
    int e1 = valid ? off[dd + 1] : 0;
#define AM_ACC(Q, V)                                        \
    {                                                       \
        float ev_ = (head ? (Q).y : (Q).x) + erd;           \
        ev_ = ev_ >= 0.f ? ev_ : 0.2f * ev_;                \
        float w_ = __expf(fminf(ev_, 80.f));                \
        a0 += w_ * b2f((ushort)(V));                        \
        a1 += w_ * b2f((ushort)((V) >> 16));                \
        s += w_;                                            \
    }
#define AM_ACCM(OK, Q, V)                                   \
    {                                                       \
        float ev_ = (head ? (Q).y : (Q).x) + erd;           \
        ev_ = ev_ >= 0.f ? ev_ : 0.2f * ev_;                \
        float w_ = (OK) ? __expf(fminf(ev_, 80.f)) : 0.f;   \
        a0 += w_ * b2f((ushort)(V));                        \
        a1 += w_ * b2f((ushort)((V) >> 16));                \
        s += w_;                                            \
    }
    for (; e + 8 <= e1; e += 8) {
        int s0 = csr[e], s1 = csr[e + 1], s2 = csr[e + 2], s3 = csr[e + 3];
        int s4 = csr[e + 4], s5 = csr[e + 5], s6 = csr[e + 6], s7 = csr[e + 7];
        float2 q0 = *(const float2*)(el + s0 * 2);
        float2 q1 = *(const float2*)(el + s1 * 2);
        float2 q2 = *(const float2*)(el + s2 * 2);
        float2 q3 = *(const float2*)(el + s3 * 2);
        float2 q4 = *(const float2*)(el + s4 * 2);
        float2 q5 = *(const float2*)(el + s5 * 2);
        float2 q6 = *(const float2*)(el + s6 * 2);
        float2 q7 = *(const float2*)(el + s7 * 2);
        uint v0 = *(const uint*)(h + (size_t)s0 * 64 + hl * 2);
        uint v1 = *(const uint*)(h + (size_t)s1 * 64 + hl * 2);
        uint v2 = *(const uint*)(h + (size_t)s2 * 64 + hl * 2);
        uint v3 = *(const uint*)(h + (size_t)s3 * 64 + hl * 2);
        uint v4 = *(const uint*)(h + (size_t)s4 * 64 + hl * 2);
        uint v5 = *(const uint*)(h + (size_t)s5 * 64 + hl * 2);
        uint v6 = *(const uint*)(h + (size_t)s6 * 64 + hl * 2);
        uint v7 = *(const uint*)(h + (size_t)s7 * 64 + hl * 2);
        AM_ACC(q0, v0) AM_ACC(q1, v1) AM_ACC(q2, v2) AM_ACC(q3, v3)
        AM_ACC(q4, v4) AM_ACC(q5, v5) AM_ACC(q6, v6) AM_ACC(q7, v7)
    }
    if (e < e1) {
        bool k1 = e + 1 < e1, k2 = e + 2 < e1, k3 = e + 3 < e1;
        bool k4 = e + 4 < e1, k5 = e + 5 < e1, k6 = e + 6 < e1, k7 = e + 7 < e1;
        int s0 = csr[e];
        int s1 = csr[k1 ? e + 1 : e];
        int s2 = csr[k2 ? e + 2 : e];
        int s3 = csr[k3 ? e + 3 : e];
        int s4 = csr[k4 ? e + 4 : e];
        int s5 = csr[k5 ? e + 5 : e];
        int s6 = csr[k6 ? e + 6 : e];
        int s7 = csr[k7 ? e + 7 : e];
        float2 q0 = *(const float2*)(el + s0 * 2);
        float2 q1 = *(const float2*)(el + s1 * 2);
        float2 q2 = *(const float2*)(el + s2 * 2);
        float2 q3 = *(const float2*)(el + s3 * 2);
        float2 q4 = *(const float2*)(el + s4 * 2);
        float2 q5 = *(const float2*)(el + s5 * 2);
        float2 q6 = *(const float2*)(el + s6 * 2);
        float2 q7 = *(const float2*)(el + s7 * 2);
        uint v0 = *(const uint*)(h + (size_t)s0 * 64 + hl * 2);
        uint v1 = *(const uint*)(h + (size_t)s1 * 64 + hl * 2);
        uint v2 = *(const uint*)(h + (size_t)s2 * 64 + hl * 2);
        uint v3 = *(const uint*)(h + (size_t)s3 * 64 + hl * 2);
        uint v4 = *(const uint*)(h + (size_t)s4 * 64 + hl * 2);
        uint v5 = *(const uint*)(h + (size_t)s5 * 64 + hl * 2);
        uint v6 = *(const uint*)(h + (size_t)s6 * 64 + hl * 2);
        uint v7 = *(const uint*)(h + (size_t)s7 * 64 + hl * 2);
        AM_ACCM(true, q0, v0) AM_ACCM(k1, q1, v1) AM_ACCM(k2, q2, v2) AM_ACCM(k3, q3, v3)
        AM_ACCM(k4, q4, v4) AM_ACCM(k5, q5, v5) AM_ACCM(k6, q6, v6) AM_ACCM(k7, q7, v7)
    }
#undef AM_ACC
#undef AM_ACCM
    float inv = 1.f / fmaxf(s, 1e-9f);
    float y0 = a0 * inv, y1 = a1 * inv;
    // head-mean: col c pairs with c+32 -> lane hl+16 within same half
    float p0 = __shfl(y0, lane + 16, 64);
    float p1 = __shfl(y1, lane + 16, 64);
    if (hl < 16) {
        red[row][2 * hl] = valid ? 0.5f * (y0 + p0) : 0.f;
        red[row][2 * hl + 1] = valid ? 0.5f * (y1 + p1) : 0.f;
        if (hl == 0) gids[row] = valid ? (gid ? gid[d] : 0) : -1;
    }
    __syncthreads();
    // block-level reduction over runs of equal gid -> few device atomics
    if (threadIdx.x < 32) {
        int c = threadIdx.x;
        float sum = 0.f;
        int cur = gids[0];
#pragma unroll
        for (int r = 0; r < 8; r++) {
            int gr = gids[r];
            if (gr != cur) {
                if (cur >= 0) atomicAdd(&out_sum[cur * 32 + c], sum);
                sum = 0.f;
                cur = gr;
            }
            if (gr >= 0) sum += red[r][c];
        }
        if (cur >= 0) atomicAdd(&out_sum[cur * 32 + c], sum);
    } else if (threadIdx.x == 32 && out_cnt) {
        float cnt = 0.f;
        int cur = gids[0];
#pragma unroll
        for (int r = 0; r < 8; r++) {
            int gr = gids[r];
            if (gr != cur) {
                if (cur >= 0) atomicAdd(&out_cnt[cur], cnt);
                cnt = 0.f;
                cur = gr;
            }
            if (gr >= 0) cnt += 1.f;
        }
        if (cur >= 0) atomicAdd(&out_cnt[cur], cnt);
    }
}

// ---------------- GraphNorm column stats (fp32 input, 8-row unroll, scalarized) ----------------
__global__ void colstats_kernel(const float* __restrict__ x,
                                float* __restrict__ sum,
                                float* __restrict__ sumsq, int Nn) {
    int C = blockDim.x, c = threadIdx.x;
    int nb = gridDim.x;
    int chunk = (Nn + nb - 1) / nb;
    int r0 = blockIdx.x * chunk;
    int r1 = min(r0 + chunk, Nn);
    float ls = 0.f, lq = 0.f;
    int r = r0;
    for (; r + 8 <= r1; r += 8) {
        const float* p = x + (size_t)r * C + c;
        float v0 = p[0];
        float v1 = p[C];
        float v2 = p[2 * C];
        float v3 = p[3 * C];
        float v4 = p[4 * C];
        float v5 = p[5 * C];
        float v6 = p[6 * C];
        float v7 = p[7 * C];
        ls += ((v0 + v1) + (v2 + v3)) + ((v4 + v5) + (v6 + v7));
        lq += ((v0 * v0 + v1 * v1) + (v2 * v2 + v3 * v3)) +
              ((v4 * v4 + v5 * v5) + (v6 * v6 + v7 * v7));
    }
    for (; r < r1; r++) {
        float v = x[(size_t)r * C + c];
        ls += v; lq += v * v;
    }
    atomicAdd(&sum[c], ls);
    atomicAdd(&sumsq[c], lq);
}

// GraphNorm apply for readout: writes d_out (per flag) + fp32 mesh input
__global__ void gnorm_apply_ro_kernel(const float* __restrict__ x,
                                      const float* __restrict__ sum,
                                      const float* __restrict__ sumsq,
                                      const float* __restrict__ g,
                                      const float* __restrict__ b,
                                      const float* __restrict__ a,
                                      void* __restrict__ doutv,
                                      const int* __restrict__ flag,
                                      float* __restrict__ rof, int Nn) {
    int c = threadIdx.x;  // C = 32
    float invn = 1.f / (float)Nn;
    float mu = sum[c] * invn, ex2 = sumsq[c] * invn;
    float av = a[c];
    float var = ex2 - 2.f * av * mu * mu + av * av * mu * mu;
    float sc = g[c] * rsqrtf(var + 1e-5f);
    float sh = b[c] - sc * av * mu;
    bool fp32 = (*flag != 0);
    for (int r = blockIdx.x; r < Nn; r += gridDim.x) {
        int i = r * 32 + c;
        float v = x[i] * sc + sh;
        rof[i] = v;
        if (fp32) ((float*)doutv)[15 + i] = v;
        else      ((ushort*)doutv)[15 + i] = f2b(v);
    }
}

// ---------------- readout: segment-mean @ pcls + leaky (fp32 out) ----------------
__global__ __launch_bounds__(256) void readout_kernel(const float* __restrict__ ro_sum,
                                                      const float* __restrict__ ro_cnt,
                                                      const float* __restrict__ pcls,
                                                      float* __restrict__ ro_lin, int NGc) {
    int idx = blockIdx.x * blockDim.x + threadIdx.x;
    int g = idx >> 5, c = idx & 31;
    if (g >= NGc) return;
    float inv = 1.f / fmaxf(ro_cnt[g], 1.f);
    float acc = 0.f;
#pragma unroll
    for (int k = 0; k < 32; k++) acc += ro_sum[g * 32 + k] * inv * pcls[k * 32 + c];
    ro_lin[g * 32 + c] = leaky(acc, 0.01f);
}

// ---------------- MFMA GEMM: C(bf16) = gnorm(A:fp32) @ B, fused gnfin + elr ----------------
template <int K, int N, int H, int LOGD, bool GN>
__global__ __launch_bounds__(256) void gemm_kernel(const float* __restrict__ A,
                                                   const float* __restrict__ B,
                                                   const float* __restrict__ csum,
                                                   const float* __restrict__ g,
                                                   const float* __restrict__ gb,
                                                   const float* __restrict__ ga,
                                                   const float* __restrict__ al,
                                                   const float* __restrict__ ar,
                                                   ushort* __restrict__ C,
                                                   float* __restrict__ el,
                                                   float* __restrict__ er, int M) {
    constexpr int NT = N / 16;
    constexpr int AROW = 40;
    __shared__ __align__(16) ushort Alds[64 * AROW];
    __shared__ __align__(16) ushort Blds[32 * N];  // [k/8][n][k%8], 16B groups
    __shared__ float ScL[256], ShL[256];
    int tid = threadIdx.x;
    int w = tid >> 6, lane = tid & 63, q = lane >> 4, l16 = lane & 15;
    int m0 = blockIdx.x * 64;
    if (GN && tid < K) {
        float invn = 1.f / (float)M;
        float mu = csum[tid] * invn, ex2 = csum[512 + tid] * invn;
        float av = ga[tid];
        float var = ex2 - 2.f * av * mu * mu + av * av * mu * mu;
        float sc = g[tid] * rsqrtf(var + 1e-5f);
        ScL[tid] = sc;
        ShL[tid] = gb[tid] - sc * av * mu;
    }
    float4v acc[NT];
#pragma unroll
    for (int nt = 0; nt < NT; nt++) acc[nt] = (float4v){0.f, 0.f, 0.f, 0.f};

    for (int kc = 0; kc < K; kc += 32) {
        __syncthreads();
        {  // stage A: fp32 -> gnorm -> bf16
#pragma unroll
            for (int it = 0; it < 2; it++) {
                int idx = it * 256 + tid;
                int r = idx >> 3;
                int c4 = (idx & 7) * 4;
                int gr = m0 + r;
                float4 av = {0.f, 0.f, 0.f, 0.f};
                if (gr < M) av = *(const float4*)(A + (size_t)gr * K + kc + c4);
                if (GN) {
                    av.x = av.x * ScL[kc + c4] + ShL[kc + c4];
                    av.y = av.y * ScL[kc + c4 + 1] + ShL[kc + c4 + 1];
                    av.z = av.z * ScL[kc + c4 + 2] + ShL[kc + c4 + 2];
                    av.w = av.w * ScL[kc + c4 + 3] + ShL[kc + c4 + 3];
                }
                uint2 pk;
                pk.x = (uint)f2b(av.x) | ((uint)f2b(av.y) << 16);
                pk.y = (uint)f2b(av.z) | ((uint)f2b(av.w) << 16);
                *(uint2*)(&Alds[r * AROW + c4]) = pk;
            }
        }
        {  // stage B: one 16B group per thread -> contiguous b128 stores, conflict-free
            constexpr int GROUPS = 4 * N;  // (32 k-rows / 8) * N
            for (int g0 = 0; g0 < GROUPS; g0 += 256) {
                int gidx = g0 + tid;
                if (GROUPS % 256 == 0 || gidx < GROUPS) {
                    int kb = gidx / N;
                    int n_ = gidx - kb * N;
                    const float* bp = B + (size_t)(kc + kb * 8) * N + n_;
                    ushort t0 = f2b(bp[0]);
                    ushort t1 = f2b(bp[N]);
                    ushort t2 = f2b(bp[2 * N]);
                    ushort t3 = f2b(bp[3 * N]);
                    ushort t4 = f2b(bp[4 * N]);
                    ushort t5 = f2b(bp[5 * N]);
                    ushort t6 = f2b(bp[6 * N]);
                    ushort t7 = f2b(bp[7 * N]);
                    uint4 pk4;
                    pk4.x = (uint)t0 | ((uint)t1 << 16);
                    pk4.y = (uint)t2 | ((uint)t3 << 16);
                    pk4.z = (uint)t4 | ((uint)t5 << 16);
                    pk4.w = (uint)t6 | ((uint)t7 << 16);
                    *(uint4*)(&Blds[(size_t)gidx * 8]) = pk4;
                }
            }
        }
        __syncthreads();
        short8 a = *(const short8*)(&Alds[(w * 16 + l16) * AROW + q * 8]);
#pragma unroll
        for (int nt = 0; nt < NT; nt++) {
            short8 b = *(const short8*)(&Blds[(q * N + nt * 16 + l16) * 8]);
            acc[nt] = __builtin_amdgcn_mfma_f32_16x16x32_bf16(a, b, acc[nt], 0, 0, 0);
        }
    }
    // store C (bf16) + fused el/er
    float pel[4][H], per[4][H];
#pragma unroll
    for (int i = 0; i < 4; i++)
#pragma unroll
        for (int hh = 0; hh < H; hh++) { pel[i][hh] = 0.f; per[i][hh] = 0.f; }
#pragma unroll
    for (int nt = 0; nt < NT; nt++) {
        int col = nt * 16 + l16;
        float alc = al[col], arc = ar[col];
        constexpr int HSH = LOGD - 4;
        int hh = nt >> HSH;
#pragma unroll
        for (int i = 0; i < 4; i++) {
            int row = m0 + w * 16 + q * 4 + i;
            float v = acc[nt][i];
            if (row < M) C[(size_t)row * N + col] = f2b(v);
            pel[i][hh] += v * alc;
            per[i][hh] += v * arc;
        }
    }
#pragma unroll
    for (int i = 0; i < 4; i++) {
#pragma unroll
        for (int hh = 0; hh < H; hh++) {
            float vl = pel[i][hh], vr = per[i][hh];
#pragma unroll
            for (int m = 1; m < 16; m <<= 1) {
                vl += __shfl_xor(vl, m, 64);
                vr += __shfl_xor(vr, m, 64);
            }
            if (l16 == 0) {
                int row = m0 + w * 16 + q * 4 + i;
                if (row < M) { el[row * H + hh] = vl; er[row * H + hh] = vr; }
            }
        }
    }
}

// ---------------- final: node-mean @ mcls ----------------
__global__ __launch_bounds__(64) void final_kernel(const float* __restrict__ msum,
                                                   const float* __restrict__ mcls,
                                                   void* __restrict__ doutv,
                                                   const int* __restrict__ flag, int Nm) {
    int t = threadIdx.x;
    if (t < 15) {
        float inv = 1.f / (float)Nm;
        float acc = 0.f;
#pragma unroll
        for (int c = 0; c < 32; c++) acc += msum[c] * inv * mcls[c * 15 + t];
        if (*flag) ((float*)doutv)[t] = acc;
        else       ((ushort*)doutv)[t] = f2b(acc);
    }
}

extern "C" void kernel_launch(void* const* d_in, const int* in_sizes, int n_in,
                              void* d_out, int out_size, void* d_ws, size_t ws_size,
                              hipStream_t stream) {
    const int NP = 100000, NG = 2000, EP = 800000, NM = 2000, EM = 32000;

    const int* patch_src = (const int*)d_in[1];
    const int* patch_dst = (const int*)d_in[2];
    const int* patch_gid = (const int*)d_in[3];
    const int* mesh_src = (const int*)d_in[4];
    const int* mesh_dst = (const int*)d_in[5];

    char* p = (char*)d_ws;
    auto alloc = [&](size_t bytes) -> char* {
        char* r = p;
        p += (bytes + 255) & ~(size_t)255;
        return r;
    };
    char* zbase = p;
    int* cnt_p = (int*)alloc((size_t)NP * 4);
    int* cursor_p = (int*)alloc((size_t)NP * 4);
    int* cnt_m = (int*)alloc((size_t)NM * 4);
    int* cursor_m = (int*)alloc((size_t)NM * 4);
    float* ro_sum = (float*)alloc((size_t)NG * 32 * 4);
    float* ro_cnt = (float*)alloc((size_t)NG * 4);
    float* msum = (float*)alloc(32 * 4);
    float* colbuf = (float*)alloc(6 * 1024 * 4);
    size_t zbytes = (size_t)(p - zbase);
    int* flag = (int*)alloc(256);
    int* off_p = (int*)alloc((size_t)(NP + 1) * 4);
    int* off_m = (int*)alloc((size_t)(NM + 1) * 4);
    int* bsum_p = (int*)alloc(64 * 4);
    int* bsum_m = (int*)alloc(16 * 4);
    int* csr_p = (int*)alloc((size_t)EP * 4);
    int* csr_m = (int*)alloc((size_t)EM * 4);
    float* el = (float*)alloc((size_t)NP * 4 * 4);
    float* er = (float*)alloc((size_t)NP * 4 * 4);
    ushort* hbuf = (ushort*)alloc((size_t)NP * 256 * 2);   // bf16 gather buffer
    float* gbuf = (float*)alloc((size_t)NP * 256 * 4);     // fp32 aggr output
    ushort* hm = (ushort*)alloc((size_t)NM * 256 * 2);
    float* gm = (float*)alloc((size_t)NM * 256 * 4);
    float* elm = (float*)alloc((size_t)NM * 4 * 4);
    float* erm = (float*)alloc((size_t)NM * 4 * 4);
    float* ro_lin = (float*)alloc((size_t)NG * 32 * 4);
    float* ro_f = (float*)alloc((size_t)NG * 32 * 4);

    ConvArgs ca;
    float* convp[36];
    int conv_idx[36];
    conv_idx[0] = 0;
    for (int i = 1; i < 36; i++) conv_idx[i] = 5 + i;
    for (int j = 0; j < 36; j++) {
        int ii = conv_idx[j];
        int n = in_sizes[ii];
        float* dd = (float*)alloc((size_t)n * 4);
        ca.s[j] = d_in[ii];
        ca.d[j] = dd;
        ca.n[j] = n;
        convp[j] = dd;
    }
    ca.s[36] = nullptr;
    ca.d[36] = (float*)zbase;
    ca.n[36] = (int)(zbytes / 4);

    const float* xf = convp[0];
    const float *pW1f = convp[1], *pal1f = convp[2], *par1f = convp[3];
    const float *pg1_gf = convp[4], *pg1_bf = convp[5], *pg1_af = convp[6];
    const float *pW2f = convp[7], *pal2f = convp[8], *par2f = convp[9];
    const float *pg2_gf = convp[10], *pg2_bf = convp[11], *pg2_af = convp[12];
    const float *pW3f = convp[13], *pal3f = convp[14], *par3f = convp[15];
    const float* pclsf = convp[16];
    const float *rn_gf = convp[17], *rn_bf2 = convp[18], *rn_af = convp[19];
    const float *mW1f = convp[20], *mal1f = convp[21], *mar1f = convp[22];
    const float *mg1_gf = convp[23], *mg1_bf = convp[24], *mg1_af = convp[25];
    const float *mW2f = convp[26], *mal2f = convp[27], *mar2f = convp[28];
    const float *mg2_gf = convp[29], *mg2_bf = convp[30], *mg2_af = convp[31];
    const float *mW3f = convp[32], *mal3f = convp[33], *mar3f = convp[34];
    const float* mclsf = convp[35];

    convert_kernel<<<dim3(16, 37), 256, 0, stream>>>(ca, (const ushort*)d_in[0], flag);

    const int SBP = (NP + 2047) / 2048, SBM = (NM + 2047) / 2048;
    hist_both<<<512 + 64, 256, 0, stream>>>(patch_dst, cnt_p, EP, mesh_dst, cnt_m, EM, 512);
    scan_both<<<SBP + SBM, 256, 0, stream>>>(cnt_p, off_p, bsum_p, NP, SBP, cnt_m, off_m, bsum_m, NM);
    fixup_both<<<SBP + SBM, 256, 0, stream>>>(bsum_p, off_p, NP, SBP, bsum_m, off_m, NM, SBM);
    scatter_both<<<512 + 64, 256, 0, stream>>>(patch_src, patch_dst, off_p, cursor_p, csr_p, EP,
                                               mesh_src, mesh_dst, off_m, cursor_m, csr_m, EM, 512);

    int gP = (NP + 3) / 4;
    int gP12 = (NP + 11) / 12;
    int gA2 = (NP + 7) / 8, gA2m = (NM + 7) / 8;
    int gP2 = (NP + 7) / 8, gM2 = (NM + 7) / 8;
    int gT = (NP + 63) / 64, gTm = (NM + 63) / 64;
    float* cb0 = colbuf + 0 * 1024;
    float* cb1 = colbuf + 1 * 1024;
    float* cb2 = colbuf + 2 * 1024;
    float* cb3 = colbuf + 3 * 1024;
    float* cb4 = colbuf + 4 * 1024;

    // ---- patch GAT layer 1 ----
    proj1_elr_kernel<<<gP, 256, 0, stream>>>(xf, pW1f, pal1f, par1f, el, er, NP);
    aggr1_fly_kernel<<<gP12, 256, 0, stream>>>(xf, pW1f, el, er, off_p, csr_p, gbuf, NP);
    colstats_kernel<<<512, 256, 0, stream>>>(gbuf, cb0, cb0 + 512, NP);

    // ---- patch GAT layer 2 ----
    gemm_kernel<256, 192, 3, 6, true><<<gT, 256, 0, stream>>>(
        gbuf, pW2f, cb0, pg1_gf, pg1_bf, pg1_af, pal2f, par2f, hbuf, el, er, NP);
    aggr4_kernel<3, 6, 192><<<gA2, 256, 0, stream>>>(hbuf, el, er, off_p, csr_p, gbuf, NP, 0.01f);
    colstats_kernel<<<512, 192, 0, stream>>>(gbuf, cb1, cb1 + 512, NP);

    // ---- patch GAT layer 3 + readout ----
    gemm_kernel<192, 64, 2, 5, true><<<gT, 256, 0, stream>>>(
        gbuf, pW3f, cb1, pg2_gf, pg2_bf, pg2_af, pal3f, par3f, hbuf, el, er, NP);
    aggr_mean_kernel<<<gP2, 256, 0, stream>>>(hbuf, el, er, off_p, csr_p, patch_gid,
                                              ro_sum, ro_cnt, NP);

    readout_kernel<<<(NG * 32 + 255) / 256, 256, 0, stream>>>(ro_sum, ro_cnt, pclsf, ro_lin, NG);
    colstats_kernel<<<64, 32, 0, stream>>>(ro_lin, cb2, cb2 + 512, NG);
    gnorm_apply_ro_kernel<<<64, 32, 0, stream>>>(ro_lin, cb2, cb2 + 512, rn_gf, rn_bf2, rn_af,
                                                 d_out, flag, ro_f, NG);

    // ---- mesh GAT layer 1 ----
    gemm_kernel<32, 256, 4, 6, false><<<gTm, 256, 0, stream>>>(
        ro_f, mW1f, nullptr, nullptr, nullptr, nullptr, mal1f, mar1f, hm, elm, erm, NM);
    aggr4_kernel<4, 6, 256><<<gA2m, 256, 0, stream>>>(hm, elm, erm, off_m, csr_m, gm, NM, 0.01f);
    colstats_kernel<<<64, 256, 0, stream>>>(gm, cb3, cb3 + 512, NM);

    // ---- mesh GAT layer 2 ----
    gemm_kernel<256, 96, 3, 5, true><<<gTm, 256, 0, stream>>>(
        gm, mW2f, cb3, mg1_gf, mg1_bf, mg1_af, mal2f, mar2f, hm, elm, erm, NM);
    aggr4_kernel<3, 5, 96><<<gA2m, 256, 0, stream>>>(hm, elm, erm, off_m, csr_m, gm, NM, 0.01f);
    colstats_kernel<<<64, 96, 0, stream>>>(gm, cb4, cb4 + 512, NM);

    // ---- mesh GAT layer 3 ----
    gemm_kernel<96, 64, 2, 5, true><<<gTm, 256, 0, stream>>>(
        gm, mW3f, cb4, mg2_gf, mg2_bf, mg2_af, mal3f, mar3f, hm, elm, erm, NM);
    aggr_mean_kernel<<<gM2, 256, 0, stream>>>(hm, elm, erm, off_m, csr_m, nullptr,
                                              msum, nullptr, NM);
    final_kernel<<<1, 64, 0, stream>>>(msum, mclsf, d_out, flag, NM);

    (void)n_in; (void)out_size; (void)ws_size;
}